// Round 11
// baseline (368.004 us; speedup 1.0000x reference)
//
#include <hip/hip_runtime.h>
#include <cstdint>
#include <cmath>

#define NEG_SLOPE 0.2f
#define BSH 6                 // 64 nodes per fine bucket
#define BR  64
#define CSH 11                // 2048 nodes per coarse bucket (32 fine buckets)
#define EBUF_CAP 8192         // max edges per fine bucket staged in LDS (avg ~2048)
#define PCHUNK 8192           // edges per partition/hist chunk

__device__ __forceinline__ float leaky(float v) { return v > 0.f ? v : NEG_SLOPE * v; }
__device__ __forceinline__ float uf(unsigned u) { return __uint_as_float(u); }

// f32 -> bf16 round-to-nearest-even (finite inputs)
__device__ __forceinline__ unsigned short f2bf(float f) {
    unsigned u = __float_as_uint(f);
    unsigned r = ((u >> 16) & 1u) + 0x7fffu;
    return (unsigned short)((u + r) >> 16);
}
__device__ __forceinline__ float bflo(unsigned q) { return __uint_as_float(q << 16); }
__device__ __forceinline__ float bfhi(unsigned q) { return __uint_as_float(q & 0xffff0000u); }

// ---------------------------------------------------------------------------
// Skinny GEMM + attention-coefficient dots + per-block As-max (NO atomics):
//   H[n,:] = bf16(X[n,:] @ W) ;  As/Ad from full-precision acc;
//   bmax[blockIdx] = max As in block  (tiny reduce kernel folds to gmax).
// ---------------------------------------------------------------------------
template <int FIN, int FOUT, int CPR, int LCPR>
__global__ __launch_bounds__(256, 4) void gemm_rows(
    const float* __restrict__ X, const float* __restrict__ W,
    const float* __restrict__ a_src, const float* __restrict__ a_dst,
    unsigned short* __restrict__ H, float* __restrict__ As, float* __restrict__ Ad,
    float* __restrict__ bmax, int N)
{
    constexpr int ROWS = 256 / CPR;
    constexpr int XST = FIN + 4;              // padded row stride (floats)
    static_assert((1 << LCPR) == CPR && CPR * 4 == FOUT, "geometry");

    __shared__ float Ws[FIN * FOUT];
    __shared__ float Xs[ROWS * XST];
    __shared__ float wmax[4];

    const int tid = threadIdx.x;
    const int base = blockIdx.x * ROWS;

    for (int i = tid; i < FIN * FOUT / 4; i += 256)
        reinterpret_cast<float4*>(Ws)[i] = reinterpret_cast<const float4*>(W)[i];

    for (int i = tid; i < ROWS * FIN / 4; i += 256) {
        int row = i / (FIN / 4);
        int k4 = (i - row * (FIN / 4)) * 4;
        float4 v = make_float4(0.f, 0.f, 0.f, 0.f);
        if (base + row < N)
            v = *reinterpret_cast<const float4*>(&X[(size_t)(base + row) * FIN + k4]);
        *reinterpret_cast<float4*>(&Xs[row * XST + k4]) = v;
    }
    __syncthreads();

    const int colg = tid & (CPR - 1);
    const int row = tid >> LCPR;
    const int c0 = colg * 4;

    float4 acc = make_float4(0.f, 0.f, 0.f, 0.f);

#pragma unroll 2
    for (int k = 0; k < FIN; k += 4) {
        float4 xv = *reinterpret_cast<const float4*>(&Xs[row * XST + k]);
        float4 w0 = *reinterpret_cast<const float4*>(&Ws[(k + 0) * FOUT + c0]);
        float4 w1 = *reinterpret_cast<const float4*>(&Ws[(k + 1) * FOUT + c0]);
        float4 w2 = *reinterpret_cast<const float4*>(&Ws[(k + 2) * FOUT + c0]);
        float4 w3 = *reinterpret_cast<const float4*>(&Ws[(k + 3) * FOUT + c0]);
        acc.x = fmaf(xv.w, w3.x, fmaf(xv.z, w2.x, fmaf(xv.y, w1.x, fmaf(xv.x, w0.x, acc.x))));
        acc.y = fmaf(xv.w, w3.y, fmaf(xv.z, w2.y, fmaf(xv.y, w1.y, fmaf(xv.x, w0.y, acc.y))));
        acc.z = fmaf(xv.w, w3.z, fmaf(xv.z, w2.z, fmaf(xv.y, w1.z, fmaf(xv.x, w0.z, acc.z))));
        acc.w = fmaf(xv.w, w3.w, fmaf(xv.z, w2.w, fmaf(xv.y, w1.w, fmaf(xv.x, w0.w, acc.w))));
    }

    const int grow = base + row;
    if (grow < N) {
        ushort4 hv;
        hv.x = f2bf(acc.x); hv.y = f2bf(acc.y);
        hv.z = f2bf(acc.z); hv.w = f2bf(acc.w);
        *reinterpret_cast<ushort4*>(&H[(size_t)grow * FOUT + c0]) = hv;
    }

    float4 asv = *reinterpret_cast<const float4*>(&a_src[c0]);
    float4 adv = *reinterpret_cast<const float4*>(&a_dst[c0]);
    float ps = acc.x * asv.x + acc.y * asv.y + acc.z * asv.z + acc.w * asv.w;
    float pd = acc.x * adv.x + acc.y * adv.y + acc.z * adv.z + acc.w * adv.w;
#pragma unroll
    for (int ofs = 1; ofs < CPR; ofs <<= 1) {
        ps += __shfl_xor(ps, ofs);
        pd += __shfl_xor(pd, ofs);
    }
    if (colg == 0 && grow < N) { As[grow] = ps; Ad[grow] = pd; }

    // block max of As -> bmax[blockIdx] (no atomics)
    float pm = (grow < N) ? ps : -3.0e38f;
#pragma unroll
    for (int ofs = 1; ofs < 64; ofs <<= 1) pm = fmaxf(pm, __shfl_xor(pm, ofs));
    if ((tid & 63) == 0) wmax[tid >> 6] = pm;
    __syncthreads();
    if (tid == 0)
        bmax[blockIdx.x] = fmaxf(fmaxf(wmax[0], wmax[1]), fmaxf(wmax[2], wmax[3]));
}

// single block: gmax = max(bmax[0..nb))
__global__ __launch_bounds__(256) void reduce_max_kernel(
    const float* __restrict__ bmax, int nb, float* __restrict__ gmax)
{
    __shared__ float sd[256];
    const int t = threadIdx.x;
    float m = -3.0e38f;
    for (int i = t; i < nb; i += 256) m = fmaxf(m, bmax[i]);
    sd[t] = m; __syncthreads();
    for (int ofs = 128; ofs; ofs >>= 1) {
        if (t < ofs) sd[t] = fmaxf(sd[t], sd[t + ofs]);
        __syncthreads();
    }
    if (t == 0) *gmax = sd[0];
}

// ---------------------------------------------------------------------------
// CSR build, atomic-free offsets:
//   chunk_hist: per 8192-edge chunk -> fine partial hist (plain writes) +
//               coarse partial counts pcT[c][chunk].
//   hist_reduce: bhist[b] = sum_i fineP[i][b]  (8-way split, few atomics).
//   bucket_scan: boff/ftail + exact per-(chunk, coarse) offsets co[chunk][c].
//   coarse_partition: scatter using co (NO global atomics).
//   fine_partition: within coarse span -> fine buckets (low-contention tails).
//   bucket_build: per-bucket LDS counting sort -> off[] + final csr.
// ---------------------------------------------------------------------------
__global__ __launch_bounds__(256) void chunk_hist(
    const int* __restrict__ dst, int* __restrict__ fineP, int* __restrict__ pcT,
    int E, int NB, int NC, int NCH)
{
    __shared__ int hc[2048];
    const int t = threadIdx.x;
    for (int i = t; i < 2048; i += 256) hc[i] = 0;
    __syncthreads();
    const int base = blockIdx.x * PCHUNK;
    const int end = (base + PCHUNK < E) ? base + PCHUNK : E;
    for (int e = base + t; e < end; e += 256)
        atomicAdd(&hc[dst[e] >> BSH], 1);
    __syncthreads();
    for (int b = t; b < NB; b += 256)
        fineP[(size_t)blockIdx.x * NB + b] = hc[b];
    if (t < NC) {
        int f0 = t << 5;
        int s = 0;
#pragma unroll
        for (int j = 0; j < 32; ++j) {
            int fb = f0 + j;
            if (fb < NB) s += hc[fb];
        }
        pcT[t * NCH + blockIdx.x] = s;
    }
}

__global__ __launch_bounds__(256) void hist_reduce(
    const int* __restrict__ fineP, int* __restrict__ bhist, int NB, int NCH)
{
    int b = blockIdx.x * 256 + threadIdx.x;
    if (b >= NB) return;
    int s = 0;
    for (int i = blockIdx.y; i < NCH; i += gridDim.y)
        s += fineP[(size_t)i * NB + b];
    atomicAdd(&bhist[b], s);
}

// single block: exclusive scan bhist -> boff, ftail; scan pcT -> co.
__global__ __launch_bounds__(256) void bucket_scan(
    const int* __restrict__ bhist, int* __restrict__ boff,
    int* __restrict__ ftail, const int* __restrict__ pcT, int* __restrict__ co,
    int NB, int NC, int NCH)
{
    __shared__ int sd[256];
    const int t = threadIdx.x;
    const int CH = (NB + 255) >> 8;
    int s = 0;
    for (int j = 0; j < CH; ++j) {
        int idx = t * CH + j;
        s += (idx < NB) ? bhist[idx] : 0;
    }
    sd[t] = s; __syncthreads();
    for (int ofs = 1; ofs < 256; ofs <<= 1) {
        int tmp = (t >= ofs) ? sd[t - ofs] : 0;
        __syncthreads();
        sd[t] += tmp;
        __syncthreads();
    }
    int run = sd[t] - s;
    for (int j = 0; j < CH; ++j) {
        int idx = t * CH + j;
        if (idx < NB) {
            boff[idx] = run;
            ftail[idx * 16] = run;
            run += bhist[idx];
        }
    }
    if (t == 255) boff[NB] = run;    // == E
    __syncthreads();
    if (t < NC) {
        int f0 = t << 5;
        int r = boff[f0 < NB ? f0 : NB];
        for (int i = 0; i < NCH; ++i) {
            co[i * 64 + t] = r;
            r += pcT[t * NCH + i];
        }
    }
}

// Pass A: partition into coarse (2048-node) buckets; offsets precomputed.
__global__ __launch_bounds__(256) void coarse_partition(
    const int* __restrict__ src, const int* __restrict__ dst,
    const int* __restrict__ co, int* __restrict__ csrA, int E, int NC)
{
    __shared__ int lcur[64], gpos[64];
    const int t = threadIdx.x;
    if (t < 64) lcur[t] = 0;
    if (t < NC) gpos[t] = co[blockIdx.x * 64 + t];
    __syncthreads();
    const int base = blockIdx.x * PCHUNK;
    int bb[32], pp[32];
#pragma unroll
    for (int i = 0; i < 32; ++i) {
        int e = base + i * 256 + t;
        bb[i] = -1;
        if (e < E) {
            int sv = src[e], dv = dst[e];
            bb[i] = dv >> CSH;
            pp[i] = (sv << CSH) | (dv & ((1 << CSH) - 1));
        }
    }
#pragma unroll
    for (int i = 0; i < 32; ++i) {
        if (bb[i] >= 0) {
            int b = bb[i];
            csrA[gpos[b] + atomicAdd(&lcur[b], 1)] = pp[i];
        }
    }
}

// Pass B: within each coarse span, partition into the 32 fine (64-node)
// buckets. Tail atomics here are low-contention (~9 per line).
__global__ __launch_bounds__(256) void fine_partition(
    const int* __restrict__ csrA, const int* __restrict__ boff,
    int* __restrict__ ftail, int* __restrict__ csrB, int NB)
{
    __shared__ int lhist[32], lcur[32], gpos[32];
    const int b = blockIdx.x;
    const int t = threadIdx.x;
    const int f0 = b << 5;
    const int fe = (f0 + 32 < NB) ? f0 + 32 : NB;
    const int cstart = boff[f0 < NB ? f0 : NB];
    const int cend = boff[fe];
    const int start = cstart + blockIdx.y * PCHUNK;
    if (start >= cend) return;
    const int end = (start + PCHUNK < cend) ? start + PCHUNK : cend;
    if (t < 32) { lhist[t] = 0; lcur[t] = 0; }
    __syncthreads();
    int ff[32], pp[32];
#pragma unroll
    for (int i = 0; i < 32; ++i) {
        int e = start + i * 256 + t;
        ff[i] = -1;
        if (e < end) {
            int v = csrA[e];
            int sv = v >> CSH, dl = v & ((1 << CSH) - 1);
            ff[i] = dl >> BSH;
            pp[i] = (sv << BSH) | (dl & (BR - 1));
            atomicAdd(&lhist[ff[i]], 1);
        }
    }
    __syncthreads();
    if (t < 32 && lhist[t]) gpos[t] = atomicAdd(&ftail[(f0 + t) * 16], lhist[t]);
    __syncthreads();
#pragma unroll
    for (int i = 0; i < 32; ++i) {
        if (ff[i] >= 0) {
            int f = ff[i];
            csrB[gpos[f] + atomicAdd(&lcur[f], 1)] = pp[i];
        }
    }
}

__global__ __launch_bounds__(256) void bucket_build(
    int* __restrict__ csr, const int* __restrict__ boff,
    int* __restrict__ off, int N, int NB)
{
    __shared__ int ebuf[EBUF_CAP];
    __shared__ int lcnt[BR];
    __shared__ int lpref[BR];
    const int bi = blockIdx.x;
    const int t = threadIdx.x;
    const int nb0 = bi << BSH;
    const int p0 = boff[bi];
    const int p1 = boff[bi + 1];
    const int cnt = p1 - p0;

    if (t < BR) lcnt[t] = 0;
    __syncthreads();
    for (int i = t; i < cnt; i += 256) {
        int v = csr[p0 + i];
        if (i < EBUF_CAP) ebuf[i] = v;
        atomicAdd(&lcnt[v & (BR - 1)], 1);
    }
    __syncthreads();
    if (t < BR) {
        int c = lcnt[t];
        int sc = c;
#pragma unroll
        for (int ofs = 1; ofs < BR; ofs <<= 1) {
            int o = __shfl_up(sc, ofs);
            if (t >= ofs) sc += o;
        }
        lpref[t] = sc - c;
        int n = nb0 + t;
        if (n < N) off[n] = p0 + sc - c;
        lcnt[t] = 0;
    }
    if (bi == NB - 1 && t == 0) off[N] = p1;
    __syncthreads();
    for (int i = t; i < cnt && i < EBUF_CAP; i += 256) {
        int v = ebuf[i];
        int ln = v & (BR - 1);
        int p = atomicAdd(&lcnt[ln], 1);
        csr[p0 + lpref[ln] + p] = v >> BSH;
    }
}

// ---------------------------------------------------------------------------
// Pull-mode GAT aggregation over bf16 value rows, no max pass (r9 version):
// softmax shifted by the global bound M = leaky(gmax + Ad[n]) >= all e.
// Per 64-edge chunk: lanes compute w in parallel into LDS; gather phase uses
// F/4 lanes per row (4 bf16 per lane, dwordx2), 64/(F/4) edges in flight,
// 4-deep unroll. f32 accumulation throughout.
// ---------------------------------------------------------------------------
template <int F, bool RELU>
__global__ __launch_bounds__(256) void gat_aggregate(
    const int* __restrict__ csr, const int* __restrict__ off,
    const float* __restrict__ As, const float* __restrict__ Ad,
    const unsigned short* __restrict__ Hb, const float* __restrict__ bias,
    const float* __restrict__ gmax, float* __restrict__ Out, int N)
{
    constexpr int LPR = F / 4;        // lanes per row
    constexpr int EPI = 64 / LPR;     // edges in flight
    constexpr unsigned RB = F * 2;    // row bytes

    __shared__ uint2 pr[4][64];
    const int wave = threadIdx.x >> 6;
    const int lane = threadIdx.x & 63;
    const int n = blockIdx.x * 4 + wave;
    if (n >= N) return;

    const int o0 = off[n];
    const int deg = off[n + 1] - o0;
    const float adn = Ad[n];
    const float eself = leaky(As[n] + adn);
    const float m = leaky(*gmax + adn);   // upper bound on all e for node n

    uint2* myp = pr[wave];
    const char* Hc = (const char*)Hb;
    const int subg = lane / LPR;
    const unsigned f8 = (unsigned)(lane & (LPR - 1)) * 8u;

    float4 acc = make_float4(0.f, 0.f, 0.f, 0.f);
    float denp = 0.f;

    for (int c = 0; c < deg; c += 64) {
        int i = c + lane;
        float w = 0.f; unsigned sb = 0;
        if (i < deg) {
            int s = csr[o0 + i];
            w = __expf(leaky(As[s] + adn) - m);
            sb = (unsigned)s * RB;
            denp += w;
        }
        myp[lane] = make_uint2(sb, __float_as_uint(w));
        int lim = (deg - c < 64) ? deg - c : 64;
        int j = subg;
        for (; j + 3 * EPI < lim; j += 4 * EPI) {
            uint2 p0 = myp[j], p1 = myp[j + EPI], p2 = myp[j + 2 * EPI], p3 = myp[j + 3 * EPI];
            uint2 q0 = *(const uint2*)(Hc + p0.x + f8);
            uint2 q1 = *(const uint2*)(Hc + p1.x + f8);
            uint2 q2 = *(const uint2*)(Hc + p2.x + f8);
            uint2 q3 = *(const uint2*)(Hc + p3.x + f8);
            float w0 = uf(p0.y), w1 = uf(p1.y), w2 = uf(p2.y), w3 = uf(p3.y);
            acc.x = fmaf(w0, bflo(q0.x), acc.x); acc.y = fmaf(w0, bfhi(q0.x), acc.y);
            acc.z = fmaf(w0, bflo(q0.y), acc.z); acc.w = fmaf(w0, bfhi(q0.y), acc.w);
            acc.x = fmaf(w1, bflo(q1.x), acc.x); acc.y = fmaf(w1, bfhi(q1.x), acc.y);
            acc.z = fmaf(w1, bflo(q1.y), acc.z); acc.w = fmaf(w1, bfhi(q1.y), acc.w);
            acc.x = fmaf(w2, bflo(q2.x), acc.x); acc.y = fmaf(w2, bfhi(q2.x), acc.y);
            acc.z = fmaf(w2, bflo(q2.y), acc.z); acc.w = fmaf(w2, bfhi(q2.y), acc.w);
            acc.x = fmaf(w3, bflo(q3.x), acc.x); acc.y = fmaf(w3, bfhi(q3.x), acc.y);
            acc.z = fmaf(w3, bflo(q3.y), acc.z); acc.w = fmaf(w3, bfhi(q3.y), acc.w);
        }
        for (; j < lim; j += EPI) {
            uint2 p = myp[j];
            uint2 q = *(const uint2*)(Hc + p.x + f8);
            float w0 = uf(p.y);
            acc.x = fmaf(w0, bflo(q.x), acc.x); acc.y = fmaf(w0, bfhi(q.x), acc.y);
            acc.z = fmaf(w0, bflo(q.y), acc.z); acc.w = fmaf(w0, bfhi(q.y), acc.w);
        }
    }

    // reduce partial acc across the EPI sub-groups (same f8, different subg)
#pragma unroll
    for (int ofs = 32; ofs >= LPR; ofs >>= 1) {
        acc.x += __shfl_xor(acc.x, ofs);
        acc.y += __shfl_xor(acc.y, ofs);
        acc.z += __shfl_xor(acc.z, ofs);
        acc.w += __shfl_xor(acc.w, ofs);
    }
    // reduce den across all 64 lanes
#pragma unroll
    for (int ofs = 1; ofs < 64; ofs <<= 1) denp += __shfl_xor(denp, ofs);

    // self-loop term + finalize
    float wsf = __expf(eself - m);
    uint2 qs = *(const uint2*)(Hc + (size_t)n * RB + f8);
    acc.x = fmaf(wsf, bflo(qs.x), acc.x); acc.y = fmaf(wsf, bfhi(qs.x), acc.y);
    acc.z = fmaf(wsf, bflo(qs.y), acc.z); acc.w = fmaf(wsf, bfhi(qs.y), acc.w);
    float den = denp + wsf;

    if (subg == 0) {
        int fi = (lane & (LPR - 1)) * 4;
        float4 bv = *reinterpret_cast<const float4*>(&bias[fi]);
        float4 v;
        v.x = acc.x / den + bv.x;
        v.y = acc.y / den + bv.y;
        v.z = acc.z / den + bv.z;
        v.w = acc.w / den + bv.w;
        if (RELU) {
            v.x = fmaxf(v.x, 0.f); v.y = fmaxf(v.y, 0.f);
            v.z = fmaxf(v.z, 0.f); v.w = fmaxf(v.w, 0.f);
        }
        *reinterpret_cast<float4*>(&Out[(size_t)n * F + fi]) = v;
    }
}

// ---------------------------------------------------------------------------
extern "C" void kernel_launch(void* const* d_in, const int* in_sizes, int n_in,
                              void* d_out, int out_size, void* d_ws, size_t ws_size,
                              hipStream_t stream)
{
    const float* x   = (const float*)d_in[0];
    const int*   ei  = (const int*)d_in[1];   // [2, E] int32
    const float* W1  = (const float*)d_in[2];
    const float* a1s = (const float*)d_in[3];
    const float* a1d = (const float*)d_in[4];
    const float* b1  = (const float*)d_in[5];
    const float* W2  = (const float*)d_in[6];
    const float* a2s = (const float*)d_in[7];
    const float* a2d = (const float*)d_in[8];
    const float* b2  = (const float*)d_in[9];

    const int N = in_sizes[0] / 128;
    const int E = in_sizes[1] / 2;
    const int NB = (N + BR - 1) >> BSH;
    const int NC = (N + (1 << CSH) - 1) >> CSH;
    const int NCH = (E + PCHUNK - 1) / PCHUNK;
    const int* src = ei;
    const int* dst = ei + E;
    float* out = (float*)d_out;

    const int g1 = (N + 31) / 32;   // layer-1 gemm grid
    const int g2 = (N + 15) / 16;   // layer-2 gemm grid

    // ---- workspace layout ----
    float* ws = (float*)d_ws;
    size_t o = 0;
    unsigned short* h1b = (unsigned short*)(ws + o); o += (size_t)N * 16;  // N*32 bf16
    float* h1a = ws + o; o += (size_t)N * 32;
    unsigned short* h2b = (unsigned short*)(ws + o); o += (size_t)N * 32;  // N*64 bf16
    float* as1 = ws + o; o += N;
    float* ad1 = ws + o; o += N;
    float* as2 = ws + o; o += N;
    float* ad2 = ws + o; o += N;
    float* bmax = ws + o; o += (size_t)g2;    // per-block maxima (g2 >= g1)
    float* gmax1 = ws + o; o += 1;
    float* gmax2 = ws + o; o += 1;
    int* ip = (int*)(ws + o);
    size_t io = 0;
    int* bhist = ip + io; io += NB;
    int* boff  = ip + io; io += (NB + 1);
    int* ftail = ip + io; io += (size_t)NB * 16;
    int* off   = ip + io; io += (N + 1);
    int* pcT   = ip + io; io += (size_t)NC * NCH;
    int* co    = ip + io; io += (size_t)NCH * 64;
    int* fineP = ip + io; io += (size_t)NCH * NB;
    int* csrA  = ip + io; io += E;
    int* csrB  = ip + io; io += E;

    // per-call state init (graph-replay safe): only bhist needs zeroing
    hipMemsetAsync(bhist, 0, (size_t)NB * sizeof(int), stream);

    // ---- CSR build (by dst), shared by both layers; atomic-free offsets ----
    chunk_hist<<<NCH, 256, 0, stream>>>(dst, fineP, pcT, E, NB, NC, NCH);
    hist_reduce<<<dim3((NB + 255) / 256, 8), 256, 0, stream>>>(fineP, bhist, NB, NCH);
    bucket_scan<<<1, 256, 0, stream>>>(bhist, boff, ftail, pcT, co, NB, NC, NCH);
    coarse_partition<<<NCH, 256, 0, stream>>>(src, dst, co, csrA, E, NC);
    fine_partition<<<dim3(NC, 9), 256, 0, stream>>>(csrA, boff, ftail, csrB, NB);
    bucket_build<<<NB, 256, 0, stream>>>(csrB, boff, off, N, NB);

    const int gn = (N + 3) / 4;

    // ---- layer 1 (FIN=128 -> 32) ----
    gemm_rows<128, 32, 8, 3><<<g1, 256, 0, stream>>>(
        x, W1, a1s, a1d, h1b, as1, ad1, bmax, N);
    reduce_max_kernel<<<1, 256, 0, stream>>>(bmax, g1, gmax1);
    gat_aggregate<32, true><<<gn, 256, 0, stream>>>(
        csrB, off, as1, ad1, h1b, b1, gmax1, h1a, N);

    // ---- layer 2 (32 -> 64) ----
    gemm_rows<32, 64, 16, 4><<<g2, 256, 0, stream>>>(
        h1a, W2, a2s, a2d, h2b, as2, ad2, bmax, N);
    reduce_max_kernel<<<1, 256, 0, stream>>>(bmax, g2, gmax2);
    gat_aggregate<64, false><<<gn, 256, 0, stream>>>(
        csrB, off, as2, ad2, h2b, b2, gmax2, out, N);
}

// Round 12
// 279.666 us; speedup vs baseline: 1.3159x; 1.3159x over previous
//
#include <hip/hip_runtime.h>
#include <cstdint>
#include <cmath>

#define NEG_SLOPE 0.2f
#define BSH 6                 // 64 nodes per fine bucket
#define BR  64
#define CSH 11                // 2048 nodes per coarse bucket (32 fine buckets)
#define EBUF_CAP 8192         // max edges per fine bucket staged in LDS (avg ~2048)
#define PCHUNK 8192           // edges per partition/hist chunk

__device__ __forceinline__ float leaky(float v) { return v > 0.f ? v : NEG_SLOPE * v; }
__device__ __forceinline__ float uf(unsigned u) { return __uint_as_float(u); }

// f32 -> bf16 round-to-nearest-even (finite inputs)
__device__ __forceinline__ unsigned short f2bf(float f) {
    unsigned u = __float_as_uint(f);
    unsigned r = ((u >> 16) & 1u) + 0x7fffu;
    return (unsigned short)((u + r) >> 16);
}
__device__ __forceinline__ float bflo(unsigned q) { return __uint_as_float(q << 16); }
__device__ __forceinline__ float bfhi(unsigned q) { return __uint_as_float(q & 0xffff0000u); }

// ---------------------------------------------------------------------------
// Skinny GEMM + attention-coefficient dots + per-block As-max (NO atomics):
//   H[n,:] = bf16(X[n,:] @ W) ;  As/Ad from full-precision acc;
//   bmax[blockIdx] = max As in block  (tiny reduce kernel folds to gmax).
// ---------------------------------------------------------------------------
template <int FIN, int FOUT, int CPR, int LCPR>
__global__ __launch_bounds__(256, 4) void gemm_rows(
    const float* __restrict__ X, const float* __restrict__ W,
    const float* __restrict__ a_src, const float* __restrict__ a_dst,
    unsigned short* __restrict__ H, float* __restrict__ As, float* __restrict__ Ad,
    float* __restrict__ bmax, int N)
{
    constexpr int ROWS = 256 / CPR;
    constexpr int XST = FIN + 4;              // padded row stride (floats)
    static_assert((1 << LCPR) == CPR && CPR * 4 == FOUT, "geometry");

    __shared__ float Ws[FIN * FOUT];
    __shared__ float Xs[ROWS * XST];
    __shared__ float wmax[4];

    const int tid = threadIdx.x;
    const int base = blockIdx.x * ROWS;

    for (int i = tid; i < FIN * FOUT / 4; i += 256)
        reinterpret_cast<float4*>(Ws)[i] = reinterpret_cast<const float4*>(W)[i];

    for (int i = tid; i < ROWS * FIN / 4; i += 256) {
        int row = i / (FIN / 4);
        int k4 = (i - row * (FIN / 4)) * 4;
        float4 v = make_float4(0.f, 0.f, 0.f, 0.f);
        if (base + row < N)
            v = *reinterpret_cast<const float4*>(&X[(size_t)(base + row) * FIN + k4]);
        *reinterpret_cast<float4*>(&Xs[row * XST + k4]) = v;
    }
    __syncthreads();

    const int colg = tid & (CPR - 1);
    const int row = tid >> LCPR;
    const int c0 = colg * 4;

    float4 acc = make_float4(0.f, 0.f, 0.f, 0.f);

#pragma unroll 2
    for (int k = 0; k < FIN; k += 4) {
        float4 xv = *reinterpret_cast<const float4*>(&Xs[row * XST + k]);
        float4 w0 = *reinterpret_cast<const float4*>(&Ws[(k + 0) * FOUT + c0]);
        float4 w1 = *reinterpret_cast<const float4*>(&Ws[(k + 1) * FOUT + c0]);
        float4 w2 = *reinterpret_cast<const float4*>(&Ws[(k + 2) * FOUT + c0]);
        float4 w3 = *reinterpret_cast<const float4*>(&Ws[(k + 3) * FOUT + c0]);
        acc.x = fmaf(xv.w, w3.x, fmaf(xv.z, w2.x, fmaf(xv.y, w1.x, fmaf(xv.x, w0.x, acc.x))));
        acc.y = fmaf(xv.w, w3.y, fmaf(xv.z, w2.y, fmaf(xv.y, w1.y, fmaf(xv.x, w0.y, acc.y))));
        acc.z = fmaf(xv.w, w3.z, fmaf(xv.z, w2.z, fmaf(xv.y, w1.z, fmaf(xv.x, w0.z, acc.z))));
        acc.w = fmaf(xv.w, w3.w, fmaf(xv.z, w2.w, fmaf(xv.y, w1.w, fmaf(xv.x, w0.w, acc.w))));
    }

    const int grow = base + row;
    if (grow < N) {
        ushort4 hv;
        hv.x = f2bf(acc.x); hv.y = f2bf(acc.y);
        hv.z = f2bf(acc.z); hv.w = f2bf(acc.w);
        *reinterpret_cast<ushort4*>(&H[(size_t)grow * FOUT + c0]) = hv;
    }

    float4 asv = *reinterpret_cast<const float4*>(&a_src[c0]);
    float4 adv = *reinterpret_cast<const float4*>(&a_dst[c0]);
    float ps = acc.x * asv.x + acc.y * asv.y + acc.z * asv.z + acc.w * asv.w;
    float pd = acc.x * adv.x + acc.y * adv.y + acc.z * adv.z + acc.w * adv.w;
#pragma unroll
    for (int ofs = 1; ofs < CPR; ofs <<= 1) {
        ps += __shfl_xor(ps, ofs);
        pd += __shfl_xor(pd, ofs);
    }
    if (colg == 0 && grow < N) { As[grow] = ps; Ad[grow] = pd; }

    // block max of As -> bmax[blockIdx] (no atomics)
    float pm = (grow < N) ? ps : -3.0e38f;
#pragma unroll
    for (int ofs = 1; ofs < 64; ofs <<= 1) pm = fmaxf(pm, __shfl_xor(pm, ofs));
    if ((tid & 63) == 0) wmax[tid >> 6] = pm;
    __syncthreads();
    if (tid == 0)
        bmax[blockIdx.x] = fmaxf(fmaxf(wmax[0], wmax[1]), fmaxf(wmax[2], wmax[3]));
}

// single block: gmax = max(bmax[0..nb))
__global__ __launch_bounds__(256) void reduce_max_kernel(
    const float* __restrict__ bmax, int nb, float* __restrict__ gmax)
{
    __shared__ float sd[256];
    const int t = threadIdx.x;
    float m = -3.0e38f;
    for (int i = t; i < nb; i += 256) m = fmaxf(m, bmax[i]);
    sd[t] = m; __syncthreads();
    for (int ofs = 128; ofs; ofs >>= 1) {
        if (t < ofs) sd[t] = fmaxf(sd[t], sd[t + ofs]);
        __syncthreads();
    }
    if (t == 0) *gmax = sd[0];
}

// ---------------------------------------------------------------------------
// CSR build, atomic-free offsets:
//   chunk_hist -> per-chunk fine hist + coarse partials pcT[c][chunk]
//   hist_reduce -> bhist ; bucket_scan -> boff/ftail
//   coarse_scan (one block per coarse bucket) -> co[chunk][c]
//   coarse_partition (no global atomics) -> fine_partition -> bucket_build
// ---------------------------------------------------------------------------
__global__ __launch_bounds__(256) void chunk_hist(
    const int* __restrict__ dst, int* __restrict__ fineP, int* __restrict__ pcT,
    int E, int NB, int NC, int NCH)
{
    __shared__ int hc[2048];
    const int t = threadIdx.x;
    for (int i = t; i < 2048; i += 256) hc[i] = 0;
    __syncthreads();
    const int base = blockIdx.x * PCHUNK;
    const int end = (base + PCHUNK < E) ? base + PCHUNK : E;
    for (int e = base + t; e < end; e += 256)
        atomicAdd(&hc[dst[e] >> BSH], 1);
    __syncthreads();
    for (int b = t; b < NB; b += 256)
        fineP[(size_t)blockIdx.x * NB + b] = hc[b];
    if (t < NC) {
        int f0 = t << 5;
        int s = 0;
#pragma unroll
        for (int j = 0; j < 32; ++j) {
            int fb = f0 + j;
            if (fb < NB) s += hc[fb];
        }
        pcT[t * NCH + blockIdx.x] = s;
    }
}

__global__ __launch_bounds__(256) void hist_reduce(
    const int* __restrict__ fineP, int* __restrict__ bhist, int NB, int NCH)
{
    int b = blockIdx.x * 256 + threadIdx.x;
    if (b >= NB) return;
    int s = 0;
    for (int i = blockIdx.y; i < NCH; i += gridDim.y)
        s += fineP[(size_t)i * NB + b];
    atomicAdd(&bhist[b], s);
}

// single block: exclusive scan bhist -> boff, ftail.
__global__ __launch_bounds__(256) void bucket_scan(
    const int* __restrict__ bhist, int* __restrict__ boff,
    int* __restrict__ ftail, int NB)
{
    __shared__ int sd[256];
    const int t = threadIdx.x;
    const int CH = (NB + 255) >> 8;
    int s = 0;
    for (int j = 0; j < CH; ++j) {
        int idx = t * CH + j;
        s += (idx < NB) ? bhist[idx] : 0;
    }
    sd[t] = s; __syncthreads();
    for (int ofs = 1; ofs < 256; ofs <<= 1) {
        int tmp = (t >= ofs) ? sd[t - ofs] : 0;
        __syncthreads();
        sd[t] += tmp;
        __syncthreads();
    }
    int run = sd[t] - s;
    for (int j = 0; j < CH; ++j) {
        int idx = t * CH + j;
        if (idx < NB) {
            boff[idx] = run;
            ftail[idx * 16] = run;
            run += bhist[idx];
        }
    }
    if (t == 255) boff[NB] = run;    // == E
}

// one block per coarse bucket: parallel prefix scan of pcT[c][*] -> co[*][c].
__global__ __launch_bounds__(256) void coarse_scan(
    const int* __restrict__ pcT, const int* __restrict__ boff,
    int* __restrict__ co, int NB, int NCH)
{
    __shared__ int sd[256];
    const int c = blockIdx.x;
    const int t = threadIdx.x;
    const int f0 = c << 5;
    const int base = boff[f0 < NB ? f0 : NB];
    int carry = 0;
    for (int start = 0; start < NCH; start += 256) {
        int idx = start + t;
        int v = (idx < NCH) ? pcT[(size_t)c * NCH + idx] : 0;
        sd[t] = v; __syncthreads();
        for (int ofs = 1; ofs < 256; ofs <<= 1) {
            int tmp = (t >= ofs) ? sd[t - ofs] : 0;
            __syncthreads();
            sd[t] += tmp;
            __syncthreads();
        }
        int incl = sd[t];
        int total = sd[255];
        if (idx < NCH) co[(size_t)idx * 64 + c] = base + carry + incl - v;
        carry += total;
        __syncthreads();
    }
}

// Pass A: partition into coarse (2048-node) buckets; offsets precomputed.
__global__ __launch_bounds__(256) void coarse_partition(
    const int* __restrict__ src, const int* __restrict__ dst,
    const int* __restrict__ co, int* __restrict__ csrA, int E, int NC)
{
    __shared__ int lcur[64], gpos[64];
    const int t = threadIdx.x;
    if (t < 64) lcur[t] = 0;
    if (t < NC) gpos[t] = co[(size_t)blockIdx.x * 64 + t];
    __syncthreads();
    const int base = blockIdx.x * PCHUNK;
    int bb[32], pp[32];
#pragma unroll
    for (int i = 0; i < 32; ++i) {
        int e = base + i * 256 + t;
        bb[i] = -1;
        if (e < E) {
            int sv = src[e], dv = dst[e];
            bb[i] = dv >> CSH;
            pp[i] = (sv << CSH) | (dv & ((1 << CSH) - 1));
        }
    }
#pragma unroll
    for (int i = 0; i < 32; ++i) {
        if (bb[i] >= 0) {
            int b = bb[i];
            csrA[gpos[b] + atomicAdd(&lcur[b], 1)] = pp[i];
        }
    }
}

// Pass B: within each coarse span, partition into the 32 fine (64-node)
// buckets. Tail atomics here are low-contention (~9 per line).
__global__ __launch_bounds__(256) void fine_partition(
    const int* __restrict__ csrA, const int* __restrict__ boff,
    int* __restrict__ ftail, int* __restrict__ csrB, int NB)
{
    __shared__ int lhist[32], lcur[32], gpos[32];
    const int b = blockIdx.x;
    const int t = threadIdx.x;
    const int f0 = b << 5;
    const int fe = (f0 + 32 < NB) ? f0 + 32 : NB;
    const int cstart = boff[f0 < NB ? f0 : NB];
    const int cend = boff[fe];
    const int start = cstart + blockIdx.y * PCHUNK;
    if (start >= cend) return;
    const int end = (start + PCHUNK < cend) ? start + PCHUNK : cend;
    if (t < 32) { lhist[t] = 0; lcur[t] = 0; }
    __syncthreads();
    int ff[32], pp[32];
#pragma unroll
    for (int i = 0; i < 32; ++i) {
        int e = start + i * 256 + t;
        ff[i] = -1;
        if (e < end) {
            int v = csrA[e];
            int sv = v >> CSH, dl = v & ((1 << CSH) - 1);
            ff[i] = dl >> BSH;
            pp[i] = (sv << BSH) | (dl & (BR - 1));
            atomicAdd(&lhist[ff[i]], 1);
        }
    }
    __syncthreads();
    if (t < 32 && lhist[t]) gpos[t] = atomicAdd(&ftail[(f0 + t) * 16], lhist[t]);
    __syncthreads();
#pragma unroll
    for (int i = 0; i < 32; ++i) {
        if (ff[i] >= 0) {
            int f = ff[i];
            csrB[gpos[f] + atomicAdd(&lcur[f], 1)] = pp[i];
        }
    }
}

__global__ __launch_bounds__(256) void bucket_build(
    int* __restrict__ csr, const int* __restrict__ boff,
    int* __restrict__ off, int N, int NB)
{
    __shared__ int ebuf[EBUF_CAP];
    __shared__ int lcnt[BR];
    __shared__ int lpref[BR];
    const int bi = blockIdx.x;
    const int t = threadIdx.x;
    const int nb0 = bi << BSH;
    const int p0 = boff[bi];
    const int p1 = boff[bi + 1];
    const int cnt = p1 - p0;

    if (t < BR) lcnt[t] = 0;
    __syncthreads();
    for (int i = t; i < cnt; i += 256) {
        int v = csr[p0 + i];
        if (i < EBUF_CAP) ebuf[i] = v;
        atomicAdd(&lcnt[v & (BR - 1)], 1);
    }
    __syncthreads();
    if (t < BR) {
        int c = lcnt[t];
        int sc = c;
#pragma unroll
        for (int ofs = 1; ofs < BR; ofs <<= 1) {
            int o = __shfl_up(sc, ofs);
            if (t >= ofs) sc += o;
        }
        lpref[t] = sc - c;
        int n = nb0 + t;
        if (n < N) off[n] = p0 + sc - c;
        lcnt[t] = 0;
    }
    if (bi == NB - 1 && t == 0) off[N] = p1;
    __syncthreads();
    for (int i = t; i < cnt && i < EBUF_CAP; i += 256) {
        int v = ebuf[i];
        int ln = v & (BR - 1);
        int p = atomicAdd(&lcnt[ln], 1);
        csr[p0 + lpref[ln] + p] = v >> BSH;
    }
}

// ---------------------------------------------------------------------------
// Pull-mode GAT aggregation over bf16 value rows, no max pass (r9 version):
// softmax shifted by the global bound M = leaky(gmax + Ad[n]) >= all e.
// Per 64-edge chunk: lanes compute w in parallel into LDS; gather phase uses
// F/4 lanes per row (4 bf16 per lane, dwordx2), 64/(F/4) edges in flight,
// 4-deep unroll. f32 accumulation throughout.
// ---------------------------------------------------------------------------
template <int F, bool RELU>
__global__ __launch_bounds__(256) void gat_aggregate(
    const int* __restrict__ csr, const int* __restrict__ off,
    const float* __restrict__ As, const float* __restrict__ Ad,
    const unsigned short* __restrict__ Hb, const float* __restrict__ bias,
    const float* __restrict__ gmax, float* __restrict__ Out, int N)
{
    constexpr int LPR = F / 4;        // lanes per row
    constexpr int EPI = 64 / LPR;     // edges in flight
    constexpr unsigned RB = F * 2;    // row bytes

    __shared__ uint2 pr[4][64];
    const int wave = threadIdx.x >> 6;
    const int lane = threadIdx.x & 63;
    const int n = blockIdx.x * 4 + wave;
    if (n >= N) return;

    const int o0 = off[n];
    const int deg = off[n + 1] - o0;
    const float adn = Ad[n];
    const float eself = leaky(As[n] + adn);
    const float m = leaky(*gmax + adn);   // upper bound on all e for node n

    uint2* myp = pr[wave];
    const char* Hc = (const char*)Hb;
    const int subg = lane / LPR;
    const unsigned f8 = (unsigned)(lane & (LPR - 1)) * 8u;

    float4 acc = make_float4(0.f, 0.f, 0.f, 0.f);
    float denp = 0.f;

    for (int c = 0; c < deg; c += 64) {
        int i = c + lane;
        float w = 0.f; unsigned sb = 0;
        if (i < deg) {
            int s = csr[o0 + i];
            w = __expf(leaky(As[s] + adn) - m);
            sb = (unsigned)s * RB;
            denp += w;
        }
        myp[lane] = make_uint2(sb, __float_as_uint(w));
        int lim = (deg - c < 64) ? deg - c : 64;
        int j = subg;
        for (; j + 3 * EPI < lim; j += 4 * EPI) {
            uint2 p0 = myp[j], p1 = myp[j + EPI], p2 = myp[j + 2 * EPI], p3 = myp[j + 3 * EPI];
            uint2 q0 = *(const uint2*)(Hc + p0.x + f8);
            uint2 q1 = *(const uint2*)(Hc + p1.x + f8);
            uint2 q2 = *(const uint2*)(Hc + p2.x + f8);
            uint2 q3 = *(const uint2*)(Hc + p3.x + f8);
            float w0 = uf(p0.y), w1 = uf(p1.y), w2 = uf(p2.y), w3 = uf(p3.y);
            acc.x = fmaf(w0, bflo(q0.x), acc.x); acc.y = fmaf(w0, bfhi(q0.x), acc.y);
            acc.z = fmaf(w0, bflo(q0.y), acc.z); acc.w = fmaf(w0, bfhi(q0.y), acc.w);
            acc.x = fmaf(w1, bflo(q1.x), acc.x); acc.y = fmaf(w1, bfhi(q1.x), acc.y);
            acc.z = fmaf(w1, bflo(q1.y), acc.z); acc.w = fmaf(w1, bfhi(q1.y), acc.w);
            acc.x = fmaf(w2, bflo(q2.x), acc.x); acc.y = fmaf(w2, bfhi(q2.x), acc.y);
            acc.z = fmaf(w2, bflo(q2.y), acc.z); acc.w = fmaf(w2, bfhi(q2.y), acc.w);
            acc.x = fmaf(w3, bflo(q3.x), acc.x); acc.y = fmaf(w3, bfhi(q3.x), acc.y);
            acc.z = fmaf(w3, bflo(q3.y), acc.z); acc.w = fmaf(w3, bfhi(q3.y), acc.w);
        }
        for (; j < lim; j += EPI) {
            uint2 p = myp[j];
            uint2 q = *(const uint2*)(Hc + p.x + f8);
            float w0 = uf(p.y);
            acc.x = fmaf(w0, bflo(q.x), acc.x); acc.y = fmaf(w0, bfhi(q.x), acc.y);
            acc.z = fmaf(w0, bflo(q.y), acc.z); acc.w = fmaf(w0, bfhi(q.y), acc.w);
        }
    }

    // reduce partial acc across the EPI sub-groups (same f8, different subg)
#pragma unroll
    for (int ofs = 32; ofs >= LPR; ofs >>= 1) {
        acc.x += __shfl_xor(acc.x, ofs);
        acc.y += __shfl_xor(acc.y, ofs);
        acc.z += __shfl_xor(acc.z, ofs);
        acc.w += __shfl_xor(acc.w, ofs);
    }
    // reduce den across all 64 lanes
#pragma unroll
    for (int ofs = 1; ofs < 64; ofs <<= 1) denp += __shfl_xor(denp, ofs);

    // self-loop term + finalize
    float wsf = __expf(eself - m);
    uint2 qs = *(const uint2*)(Hc + (size_t)n * RB + f8);
    acc.x = fmaf(wsf, bflo(qs.x), acc.x); acc.y = fmaf(wsf, bfhi(qs.x), acc.y);
    acc.z = fmaf(wsf, bflo(qs.y), acc.z); acc.w = fmaf(wsf, bfhi(qs.y), acc.w);
    float den = denp + wsf;

    if (subg == 0) {
        int fi = (lane & (LPR - 1)) * 4;
        float4 bv = *reinterpret_cast<const float4*>(&bias[fi]);
        float4 v;
        v.x = acc.x / den + bv.x;
        v.y = acc.y / den + bv.y;
        v.z = acc.z / den + bv.z;
        v.w = acc.w / den + bv.w;
        if (RELU) {
            v.x = fmaxf(v.x, 0.f); v.y = fmaxf(v.y, 0.f);
            v.z = fmaxf(v.z, 0.f); v.w = fmaxf(v.w, 0.f);
        }
        *reinterpret_cast<float4*>(&Out[(size_t)n * F + fi]) = v;
    }
}

// ---------------------------------------------------------------------------
extern "C" void kernel_launch(void* const* d_in, const int* in_sizes, int n_in,
                              void* d_out, int out_size, void* d_ws, size_t ws_size,
                              hipStream_t stream)
{
    const float* x   = (const float*)d_in[0];
    const int*   ei  = (const int*)d_in[1];   // [2, E] int32
    const float* W1  = (const float*)d_in[2];
    const float* a1s = (const float*)d_in[3];
    const float* a1d = (const float*)d_in[4];
    const float* b1  = (const float*)d_in[5];
    const float* W2  = (const float*)d_in[6];
    const float* a2s = (const float*)d_in[7];
    const float* a2d = (const float*)d_in[8];
    const float* b2  = (const float*)d_in[9];

    const int N = in_sizes[0] / 128;
    const int E = in_sizes[1] / 2;
    const int NB = (N + BR - 1) >> BSH;
    const int NC = (N + (1 << CSH) - 1) >> CSH;
    const int NCH = (E + PCHUNK - 1) / PCHUNK;
    const int* src = ei;
    const int* dst = ei + E;
    float* out = (float*)d_out;

    const int g1 = (N + 31) / 32;   // layer-1 gemm grid
    const int g2 = (N + 15) / 16;   // layer-2 gemm grid

    // ---- workspace layout ----
    float* ws = (float*)d_ws;
    size_t o = 0;
    unsigned short* h1b = (unsigned short*)(ws + o); o += (size_t)N * 16;  // N*32 bf16
    float* h1a = ws + o; o += (size_t)N * 32;
    unsigned short* h2b = (unsigned short*)(ws + o); o += (size_t)N * 32;  // N*64 bf16
    float* as1 = ws + o; o += N;
    float* ad1 = ws + o; o += N;
    float* as2 = ws + o; o += N;
    float* ad2 = ws + o; o += N;
    float* bmax = ws + o; o += (size_t)g2;    // per-block maxima (g2 >= g1)
    float* gmax1 = ws + o; o += 1;
    float* gmax2 = ws + o; o += 1;
    int* ip = (int*)(ws + o);
    size_t io = 0;
    int* bhist = ip + io; io += NB;
    int* boff  = ip + io; io += (NB + 1);
    int* ftail = ip + io; io += (size_t)NB * 16;
    int* off   = ip + io; io += (N + 1);
    int* pcT   = ip + io; io += (size_t)NC * NCH;
    int* co    = ip + io; io += (size_t)NCH * 64;
    int* fineP = ip + io; io += (size_t)NCH * NB;
    int* csrA  = ip + io; io += E;
    int* csrB  = ip + io; io += E;

    // per-call state init (graph-replay safe): only bhist needs zeroing
    hipMemsetAsync(bhist, 0, (size_t)NB * sizeof(int), stream);

    // ---- CSR build (by dst), shared by both layers; atomic-free offsets ----
    chunk_hist<<<NCH, 256, 0, stream>>>(dst, fineP, pcT, E, NB, NC, NCH);
    hist_reduce<<<dim3((NB + 255) / 256, 8), 256, 0, stream>>>(fineP, bhist, NB, NCH);
    bucket_scan<<<1, 256, 0, stream>>>(bhist, boff, ftail, NB);
    coarse_scan<<<NC, 256, 0, stream>>>(pcT, boff, co, NB, NCH);
    coarse_partition<<<NCH, 256, 0, stream>>>(src, dst, co, csrA, E, NC);
    fine_partition<<<dim3(NC, 9), 256, 0, stream>>>(csrA, boff, ftail, csrB, NB);
    bucket_build<<<NB, 256, 0, stream>>>(csrB, boff, off, N, NB);

    const int gn = (N + 3) / 4;

    // ---- layer 1 (FIN=128 -> 32) ----
    gemm_rows<128, 32, 8, 3><<<g1, 256, 0, stream>>>(
        x, W1, a1s, a1d, h1b, as1, ad1, bmax, N);
    reduce_max_kernel<<<1, 256, 0, stream>>>(bmax, g1, gmax1);
    gat_aggregate<32, true><<<gn, 256, 0, stream>>>(
        csrB, off, as1, ad1, h1b, b1, gmax1, h1a, N);

    // ---- layer 2 (32 -> 64) ----
    gemm_rows<32, 64, 16, 4><<<g2, 256, 0, stream>>>(
        h1a, W2, a2s, a2d, h2b, as2, ad2, bmax, N);
    reduce_max_kernel<<<1, 256, 0, stream>>>(bmax, g2, gmax2);
    gat_aggregate<64, false><<<gn, 256, 0, stream>>>(
        csrB, off, as2, ad2, h2b, b2, gmax2, out, N);
}

// Round 13
// 265.256 us; speedup vs baseline: 1.3874x; 1.0543x over previous
//
#include <hip/hip_runtime.h>
#include <cstdint>
#include <cmath>

#define NEG_SLOPE 0.2f
#define BSH 6                 // 64-node granularity for chunk_hist LDS hist
#define CSH 9                 // 512 nodes per coarse bucket
#define CBN 512               // 1 << CSH
#define RATIO 8               // CBN / 64
#define PCHUNK 8192           // edges per partition/hist chunk

__device__ __forceinline__ float leaky(float v) { return v > 0.f ? v : NEG_SLOPE * v; }
__device__ __forceinline__ float uf(unsigned u) { return __uint_as_float(u); }

// f32 -> bf16 round-to-nearest-even (finite inputs)
__device__ __forceinline__ unsigned short f2bf(float f) {
    unsigned u = __float_as_uint(f);
    unsigned r = ((u >> 16) & 1u) + 0x7fffu;
    return (unsigned short)((u + r) >> 16);
}
__device__ __forceinline__ float bflo(unsigned q) { return __uint_as_float(q << 16); }
__device__ __forceinline__ float bfhi(unsigned q) { return __uint_as_float(q & 0xffff0000u); }

// ---------------------------------------------------------------------------
// Skinny GEMM + attention-coefficient dots + per-block As-max (NO atomics):
//   H[n,:] = bf16(X[n,:] @ W) ;  As/Ad from full-precision acc;
//   bmax[blockIdx] = max As in block  (tiny reduce kernel folds to gmax).
// ---------------------------------------------------------------------------
template <int FIN, int FOUT, int CPR, int LCPR>
__global__ __launch_bounds__(256, 4) void gemm_rows(
    const float* __restrict__ X, const float* __restrict__ W,
    const float* __restrict__ a_src, const float* __restrict__ a_dst,
    unsigned short* __restrict__ H, float* __restrict__ As, float* __restrict__ Ad,
    float* __restrict__ bmax, int N)
{
    constexpr int ROWS = 256 / CPR;
    constexpr int XST = FIN + 4;              // padded row stride (floats)
    static_assert((1 << LCPR) == CPR && CPR * 4 == FOUT, "geometry");

    __shared__ float Ws[FIN * FOUT];
    __shared__ float Xs[ROWS * XST];
    __shared__ float wmax[4];

    const int tid = threadIdx.x;
    const int base = blockIdx.x * ROWS;

    for (int i = tid; i < FIN * FOUT / 4; i += 256)
        reinterpret_cast<float4*>(Ws)[i] = reinterpret_cast<const float4*>(W)[i];

    for (int i = tid; i < ROWS * FIN / 4; i += 256) {
        int row = i / (FIN / 4);
        int k4 = (i - row * (FIN / 4)) * 4;
        float4 v = make_float4(0.f, 0.f, 0.f, 0.f);
        if (base + row < N)
            v = *reinterpret_cast<const float4*>(&X[(size_t)(base + row) * FIN + k4]);
        *reinterpret_cast<float4*>(&Xs[row * XST + k4]) = v;
    }
    __syncthreads();

    const int colg = tid & (CPR - 1);
    const int row = tid >> LCPR;
    const int c0 = colg * 4;

    float4 acc = make_float4(0.f, 0.f, 0.f, 0.f);

#pragma unroll 2
    for (int k = 0; k < FIN; k += 4) {
        float4 xv = *reinterpret_cast<const float4*>(&Xs[row * XST + k]);
        float4 w0 = *reinterpret_cast<const float4*>(&Ws[(k + 0) * FOUT + c0]);
        float4 w1 = *reinterpret_cast<const float4*>(&Ws[(k + 1) * FOUT + c0]);
        float4 w2 = *reinterpret_cast<const float4*>(&Ws[(k + 2) * FOUT + c0]);
        float4 w3 = *reinterpret_cast<const float4*>(&Ws[(k + 3) * FOUT + c0]);
        acc.x = fmaf(xv.w, w3.x, fmaf(xv.z, w2.x, fmaf(xv.y, w1.x, fmaf(xv.x, w0.x, acc.x))));
        acc.y = fmaf(xv.w, w3.y, fmaf(xv.z, w2.y, fmaf(xv.y, w1.y, fmaf(xv.x, w0.y, acc.y))));
        acc.z = fmaf(xv.w, w3.z, fmaf(xv.z, w2.z, fmaf(xv.y, w1.z, fmaf(xv.x, w0.z, acc.z))));
        acc.w = fmaf(xv.w, w3.w, fmaf(xv.z, w2.w, fmaf(xv.y, w1.w, fmaf(xv.x, w0.w, acc.w))));
    }

    const int grow = base + row;
    if (grow < N) {
        ushort4 hv;
        hv.x = f2bf(acc.x); hv.y = f2bf(acc.y);
        hv.z = f2bf(acc.z); hv.w = f2bf(acc.w);
        *reinterpret_cast<ushort4*>(&H[(size_t)grow * FOUT + c0]) = hv;
    }

    float4 asv = *reinterpret_cast<const float4*>(&a_src[c0]);
    float4 adv = *reinterpret_cast<const float4*>(&a_dst[c0]);
    float ps = acc.x * asv.x + acc.y * asv.y + acc.z * asv.z + acc.w * asv.w;
    float pd = acc.x * adv.x + acc.y * adv.y + acc.z * adv.z + acc.w * adv.w;
#pragma unroll
    for (int ofs = 1; ofs < CPR; ofs <<= 1) {
        ps += __shfl_xor(ps, ofs);
        pd += __shfl_xor(pd, ofs);
    }
    if (colg == 0 && grow < N) { As[grow] = ps; Ad[grow] = pd; }

    // block max of As -> bmax[blockIdx] (no atomics)
    float pm = (grow < N) ? ps : -3.0e38f;
#pragma unroll
    for (int ofs = 1; ofs < 64; ofs <<= 1) pm = fmaxf(pm, __shfl_xor(pm, ofs));
    if ((tid & 63) == 0) wmax[tid >> 6] = pm;
    __syncthreads();
    if (tid == 0)
        bmax[blockIdx.x] = fmaxf(fmaxf(wmax[0], wmax[1]), fmaxf(wmax[2], wmax[3]));
}

// single block: gmax = max(bmax[0..nb))
__global__ __launch_bounds__(256) void reduce_max_kernel(
    const float* __restrict__ bmax, int nb, float* __restrict__ gmax)
{
    __shared__ float sd[256];
    const int t = threadIdx.x;
    float m = -3.0e38f;
    for (int i = t; i < nb; i += 256) m = fmaxf(m, bmax[i]);
    sd[t] = m; __syncthreads();
    for (int ofs = 128; ofs; ofs >>= 1) {
        if (t < ofs) sd[t] = fmaxf(sd[t], sd[t + ofs]);
        __syncthreads();
    }
    if (t == 0) *gmax = sd[0];
}

// ---------------------------------------------------------------------------
// CSR build, 6 kernels, zero global atomics, no per-call memset:
//   chunk_hist   : per 8192-edge chunk -> coarse partials pcT[c][chunk]
//   coarse_total : totals[c] = sum_chunks pcT
//   boffc_scan   : exclusive scan totals -> boffC
//   coarse_scan  : prefix pcT -> exact per-(chunk,c) offsets co[chunk][c]
//   coarse_partition: scatter packed (src<<9 | dst&511) into coarse spans
//   node_sort    : per coarse bucket, LDS counting sort by node -> off, csr
// ---------------------------------------------------------------------------
__global__ __launch_bounds__(256) void chunk_hist(
    const int* __restrict__ dst, int* __restrict__ pcT,
    int E, int NB, int NCC, int NCH)
{
    __shared__ int hc[2048];
    const int t = threadIdx.x;
    for (int i = t; i < 2048; i += 256) hc[i] = 0;
    __syncthreads();
    const int base = blockIdx.x * PCHUNK;
    const int end = (base + PCHUNK < E) ? base + PCHUNK : E;
    for (int e = base + t; e < end; e += 256)
        atomicAdd(&hc[dst[e] >> BSH], 1);
    __syncthreads();
    if (t < NCC) {
        int f0 = t * RATIO;
        int s = 0;
#pragma unroll
        for (int j = 0; j < RATIO; ++j) {
            int fb = f0 + j;
            if (fb < NB) s += hc[fb];
        }
        pcT[(size_t)t * NCH + blockIdx.x] = s;
    }
}

__global__ __launch_bounds__(256) void coarse_total(
    const int* __restrict__ pcT, int* __restrict__ totals, int NCH)
{
    __shared__ int sd[256];
    const int t = threadIdx.x;
    int s = 0;
    for (int i = t; i < NCH; i += 256)
        s += pcT[(size_t)blockIdx.x * NCH + i];
    sd[t] = s; __syncthreads();
    for (int ofs = 128; ofs; ofs >>= 1) {
        if (t < ofs) sd[t] += sd[t + ofs];
        __syncthreads();
    }
    if (t == 0) totals[blockIdx.x] = sd[0];
}

// single block: exclusive scan totals[0..NCC) -> boffC[0..NCC]
__global__ __launch_bounds__(256) void boffc_scan(
    const int* __restrict__ totals, int* __restrict__ boffC, int NCC)
{
    __shared__ int sd[256];
    const int t = threadIdx.x;
    int v = (t < NCC) ? totals[t] : 0;
    sd[t] = v; __syncthreads();
    for (int ofs = 1; ofs < 256; ofs <<= 1) {
        int tmp = (t >= ofs) ? sd[t - ofs] : 0;
        __syncthreads();
        sd[t] += tmp;
        __syncthreads();
    }
    if (t < NCC) boffC[t] = sd[t] - v;
    if (t == 255) boffC[NCC] = sd[255];   // == E
}

// one block per coarse bucket: parallel prefix scan of pcT[c][*] -> co[*][c].
__global__ __launch_bounds__(256) void coarse_scan(
    const int* __restrict__ pcT, const int* __restrict__ boffC,
    int* __restrict__ co, int NCH)
{
    __shared__ int sd[256];
    const int c = blockIdx.x;
    const int t = threadIdx.x;
    const int base = boffC[c];
    int carry = 0;
    for (int start = 0; start < NCH; start += 256) {
        int idx = start + t;
        int v = (idx < NCH) ? pcT[(size_t)c * NCH + idx] : 0;
        sd[t] = v; __syncthreads();
        for (int ofs = 1; ofs < 256; ofs <<= 1) {
            int tmp = (t >= ofs) ? sd[t - ofs] : 0;
            __syncthreads();
            sd[t] += tmp;
            __syncthreads();
        }
        int incl = sd[t];
        int total = sd[255];
        if (idx < NCH) co[(size_t)idx * 256 + c] = base + carry + incl - v;
        carry += total;
        __syncthreads();
    }
}

// Pass A: partition into coarse (512-node) buckets; offsets precomputed.
__global__ __launch_bounds__(256) void coarse_partition(
    const int* __restrict__ src, const int* __restrict__ dst,
    const int* __restrict__ co, int* __restrict__ csrA, int E, int NCC)
{
    __shared__ int lcur[256], gpos[256];
    const int t = threadIdx.x;
    lcur[t] = 0;
    if (t < NCC) gpos[t] = co[(size_t)blockIdx.x * 256 + t];
    __syncthreads();
    const int base = blockIdx.x * PCHUNK;
    int bb[32], pp[32];
#pragma unroll
    for (int i = 0; i < 32; ++i) {
        int e = base + i * 256 + t;
        bb[i] = -1;
        if (e < E) {
            int sv = src[e], dv = dst[e];
            bb[i] = dv >> CSH;
            pp[i] = (sv << CSH) | (dv & (CBN - 1));
        }
    }
#pragma unroll
    for (int i = 0; i < 32; ++i) {
        if (bb[i] >= 0) {
            int b = bb[i];
            csrA[gpos[b] + atomicAdd(&lcur[b], 1)] = pp[i];
        }
    }
}

// one block per coarse bucket: node-level LDS counting sort over its span.
// Pass 1: count + 512-wide scan -> off[]; pass 2: scatter to final csr.
__global__ __launch_bounds__(256) void node_sort(
    const int* __restrict__ csrA, const int* __restrict__ boffC,
    int* __restrict__ off, int* __restrict__ csr, int N, int NCC, int E)
{
    __shared__ int cnt[CBN];
    __shared__ int pref[CBN];
    __shared__ int sd[256];
    const int c = blockIdx.x;
    const int t = threadIdx.x;
    const int p0 = boffC[c];
    const int p1 = boffC[c + 1];
    const int n0 = c << CSH;

    for (int i = t; i < CBN; i += 256) cnt[i] = 0;
    __syncthreads();
    // pass 1: count (coalesced span read, L2-resident)
    for (int i = p0 + t; i < p1; i += 256)
        atomicAdd(&cnt[csrA[i] & (CBN - 1)], 1);
    __syncthreads();
    // exclusive scan of cnt[0..512): pair-per-thread + 256-wide scan
    int a0 = cnt[2 * t], a1 = cnt[2 * t + 1];
    int pairsum = a0 + a1;
    sd[t] = pairsum; __syncthreads();
    for (int ofs = 1; ofs < 256; ofs <<= 1) {
        int tmp = (t >= ofs) ? sd[t - ofs] : 0;
        __syncthreads();
        sd[t] += tmp;
        __syncthreads();
    }
    int run = sd[t] - pairsum;
    pref[2 * t] = run;
    pref[2 * t + 1] = run + a0;
    int n = n0 + 2 * t;
    if (n < N) off[n] = p0 + run;
    if (n + 1 < N) off[n + 1] = p0 + run + a0;
    if (c == NCC - 1 && t == 0) off[N] = E;
    __syncthreads();
    for (int i = t; i < CBN; i += 256) cnt[i] = 0;   // reuse as cursors
    __syncthreads();
    // pass 2: scatter (span re-read from L2; writes stay within span)
    for (int i = p0 + t; i < p1; i += 256) {
        int v = csrA[i];
        int ln = v & (CBN - 1);
        int p = atomicAdd(&cnt[ln], 1);
        csr[p0 + pref[ln] + p] = v >> CSH;
    }
}

// ---------------------------------------------------------------------------
// Pull-mode GAT aggregation over bf16 value rows, no max pass (r9/r12 form):
// softmax shifted by the global bound M = leaky(gmax + Ad[n]) >= all e.
// Per 64-edge chunk: lanes compute w in parallel into LDS; gather phase uses
// F/4 lanes per row (4 bf16 per lane, dwordx2), 64/(F/4) edges in flight,
// 4-deep unroll. f32 accumulation throughout.
// ---------------------------------------------------------------------------
template <int F, bool RELU>
__global__ __launch_bounds__(256) void gat_aggregate(
    const int* __restrict__ csr, const int* __restrict__ off,
    const float* __restrict__ As, const float* __restrict__ Ad,
    const unsigned short* __restrict__ Hb, const float* __restrict__ bias,
    const float* __restrict__ gmax, float* __restrict__ Out, int N)
{
    constexpr int LPR = F / 4;        // lanes per row
    constexpr int EPI = 64 / LPR;     // edges in flight
    constexpr unsigned RB = F * 2;    // row bytes

    __shared__ uint2 pr[4][64];
    const int wave = threadIdx.x >> 6;
    const int lane = threadIdx.x & 63;
    const int n = blockIdx.x * 4 + wave;
    if (n >= N) return;

    const int o0 = off[n];
    const int deg = off[n + 1] - o0;
    const float adn = Ad[n];
    const float eself = leaky(As[n] + adn);
    const float m = leaky(*gmax + adn);   // upper bound on all e for node n

    uint2* myp = pr[wave];
    const char* Hc = (const char*)Hb;
    const int subg = lane / LPR;
    const unsigned f8 = (unsigned)(lane & (LPR - 1)) * 8u;

    float4 acc = make_float4(0.f, 0.f, 0.f, 0.f);
    float denp = 0.f;

    for (int c = 0; c < deg; c += 64) {
        int i = c + lane;
        float w = 0.f; unsigned sb = 0;
        if (i < deg) {
            int s = csr[o0 + i];
            w = __expf(leaky(As[s] + adn) - m);
            sb = (unsigned)s * RB;
            denp += w;
        }
        myp[lane] = make_uint2(sb, __float_as_uint(w));
        int lim = (deg - c < 64) ? deg - c : 64;
        int j = subg;
        for (; j + 3 * EPI < lim; j += 4 * EPI) {
            uint2 p0 = myp[j], p1 = myp[j + EPI], p2 = myp[j + 2 * EPI], p3 = myp[j + 3 * EPI];
            uint2 q0 = *(const uint2*)(Hc + p0.x + f8);
            uint2 q1 = *(const uint2*)(Hc + p1.x + f8);
            uint2 q2 = *(const uint2*)(Hc + p2.x + f8);
            uint2 q3 = *(const uint2*)(Hc + p3.x + f8);
            float w0 = uf(p0.y), w1 = uf(p1.y), w2 = uf(p2.y), w3 = uf(p3.y);
            acc.x = fmaf(w0, bflo(q0.x), acc.x); acc.y = fmaf(w0, bfhi(q0.x), acc.y);
            acc.z = fmaf(w0, bflo(q0.y), acc.z); acc.w = fmaf(w0, bfhi(q0.y), acc.w);
            acc.x = fmaf(w1, bflo(q1.x), acc.x); acc.y = fmaf(w1, bfhi(q1.x), acc.y);
            acc.z = fmaf(w1, bflo(q1.y), acc.z); acc.w = fmaf(w1, bfhi(q1.y), acc.w);
            acc.x = fmaf(w2, bflo(q2.x), acc.x); acc.y = fmaf(w2, bfhi(q2.x), acc.y);
            acc.z = fmaf(w2, bflo(q2.y), acc.z); acc.w = fmaf(w2, bfhi(q2.y), acc.w);
            acc.x = fmaf(w3, bflo(q3.x), acc.x); acc.y = fmaf(w3, bfhi(q3.x), acc.y);
            acc.z = fmaf(w3, bflo(q3.y), acc.z); acc.w = fmaf(w3, bfhi(q3.y), acc.w);
        }
        for (; j < lim; j += EPI) {
            uint2 p = myp[j];
            uint2 q = *(const uint2*)(Hc + p.x + f8);
            float w0 = uf(p.y);
            acc.x = fmaf(w0, bflo(q.x), acc.x); acc.y = fmaf(w0, bfhi(q.x), acc.y);
            acc.z = fmaf(w0, bflo(q.y), acc.z); acc.w = fmaf(w0, bfhi(q.y), acc.w);
        }
    }

    // reduce partial acc across the EPI sub-groups (same f8, different subg)
#pragma unroll
    for (int ofs = 32; ofs >= LPR; ofs >>= 1) {
        acc.x += __shfl_xor(acc.x, ofs);
        acc.y += __shfl_xor(acc.y, ofs);
        acc.z += __shfl_xor(acc.z, ofs);
        acc.w += __shfl_xor(acc.w, ofs);
    }
    // reduce den across all 64 lanes
#pragma unroll
    for (int ofs = 1; ofs < 64; ofs <<= 1) denp += __shfl_xor(denp, ofs);

    // self-loop term + finalize
    float wsf = __expf(eself - m);
    uint2 qs = *(const uint2*)(Hc + (size_t)n * RB + f8);
    acc.x = fmaf(wsf, bflo(qs.x), acc.x); acc.y = fmaf(wsf, bfhi(qs.x), acc.y);
    acc.z = fmaf(wsf, bflo(qs.y), acc.z); acc.w = fmaf(wsf, bfhi(qs.y), acc.w);
    float den = denp + wsf;

    if (subg == 0) {
        int fi = (lane & (LPR - 1)) * 4;
        float4 bv = *reinterpret_cast<const float4*>(&bias[fi]);
        float4 v;
        v.x = acc.x / den + bv.x;
        v.y = acc.y / den + bv.y;
        v.z = acc.z / den + bv.z;
        v.w = acc.w / den + bv.w;
        if (RELU) {
            v.x = fmaxf(v.x, 0.f); v.y = fmaxf(v.y, 0.f);
            v.z = fmaxf(v.z, 0.f); v.w = fmaxf(v.w, 0.f);
        }
        *reinterpret_cast<float4*>(&Out[(size_t)n * F + fi]) = v;
    }
}

// ---------------------------------------------------------------------------
extern "C" void kernel_launch(void* const* d_in, const int* in_sizes, int n_in,
                              void* d_out, int out_size, void* d_ws, size_t ws_size,
                              hipStream_t stream)
{
    const float* x   = (const float*)d_in[0];
    const int*   ei  = (const int*)d_in[1];   // [2, E] int32
    const float* W1  = (const float*)d_in[2];
    const float* a1s = (const float*)d_in[3];
    const float* a1d = (const float*)d_in[4];
    const float* b1  = (const float*)d_in[5];
    const float* W2  = (const float*)d_in[6];
    const float* a2s = (const float*)d_in[7];
    const float* a2d = (const float*)d_in[8];
    const float* b2  = (const float*)d_in[9];

    const int N = in_sizes[0] / 128;
    const int E = in_sizes[1] / 2;
    const int NB = (N + 63) >> BSH;                 // 64-node fine granularity
    const int NCC = (N + CBN - 1) >> CSH;           // coarse buckets (<=256)
    const int NCH = (E + PCHUNK - 1) / PCHUNK;
    const int* src = ei;
    const int* dst = ei + E;
    float* out = (float*)d_out;

    const int g1 = (N + 31) / 32;   // layer-1 gemm grid
    const int g2 = (N + 15) / 16;   // layer-2 gemm grid

    // ---- workspace layout ----
    float* ws = (float*)d_ws;
    size_t o = 0;
    unsigned short* h1b = (unsigned short*)(ws + o); o += (size_t)N * 16;  // N*32 bf16
    float* h1a = ws + o; o += (size_t)N * 32;
    unsigned short* h2b = (unsigned short*)(ws + o); o += (size_t)N * 32;  // N*64 bf16
    float* as1 = ws + o; o += N;
    float* ad1 = ws + o; o += N;
    float* as2 = ws + o; o += N;
    float* ad2 = ws + o; o += N;
    float* bmax = ws + o; o += (size_t)g2;    // per-block maxima (g2 >= g1)
    float* gmax1 = ws + o; o += 1;
    float* gmax2 = ws + o; o += 1;
    int* ip = (int*)(ws + o);
    size_t io = 0;
    int* pcT    = ip + io; io += (size_t)NCC * NCH;
    int* totals = ip + io; io += NCC;
    int* boffC  = ip + io; io += (NCC + 1);
    int* co     = ip + io; io += (size_t)NCH * 256;
    int* off    = ip + io; io += (N + 1);
    int* csrA   = ip + io; io += E;
    int* csr    = ip + io; io += E;

    // NOTE: no per-call memset needed — every buffer is fully rewritten.

    // ---- CSR build (by dst), shared by both layers; zero global atomics ----
    chunk_hist<<<NCH, 256, 0, stream>>>(dst, pcT, E, NB, NCC, NCH);
    coarse_total<<<NCC, 256, 0, stream>>>(pcT, totals, NCH);
    boffc_scan<<<1, 256, 0, stream>>>(totals, boffC, NCC);
    coarse_scan<<<NCC, 256, 0, stream>>>(pcT, boffC, co, NCH);
    coarse_partition<<<NCH, 256, 0, stream>>>(src, dst, co, csrA, E, NCC);
    node_sort<<<NCC, 256, 0, stream>>>(csrA, boffC, off, csr, N, NCC, E);

    const int gn = (N + 3) / 4;

    // ---- layer 1 (FIN=128 -> 32) ----
    gemm_rows<128, 32, 8, 3><<<g1, 256, 0, stream>>>(
        x, W1, a1s, a1d, h1b, as1, ad1, bmax, N);
    reduce_max_kernel<<<1, 256, 0, stream>>>(bmax, g1, gmax1);
    gat_aggregate<32, true><<<gn, 256, 0, stream>>>(
        csr, off, as1, ad1, h1b, b1, gmax1, h1a, N);

    // ---- layer 2 (32 -> 64) ----
    gemm_rows<32, 64, 16, 4><<<g2, 256, 0, stream>>>(
        h1a, W2, a2s, a2d, h2b, as2, ad2, bmax, N);
    reduce_max_kernel<<<1, 256, 0, stream>>>(bmax, g2, gmax2);
    gat_aggregate<64, false><<<gn, 256, 0, stream>>>(
        csr, off, as2, ad2, h2b, b2, gmax2, out, N);
}

// Round 15
// 257.042 us; speedup vs baseline: 1.4317x; 1.0320x over previous
//
#include <hip/hip_runtime.h>
#include <cstdint>
#include <cmath>

#define NEG_SLOPE 0.2f
#define BSH 6                 // 64-node granularity for chunk_hist LDS hist
#define CSH 9                 // 512 nodes per coarse bucket
#define CBN 512               // 1 << CSH
#define RATIO 8               // CBN / 64
#define PCHUNK 8192           // edges per partition/hist chunk

__device__ __forceinline__ float leaky(float v) { return v > 0.f ? v : NEG_SLOPE * v; }
__device__ __forceinline__ float uf(unsigned u) { return __uint_as_float(u); }

// f32 -> bf16 round-to-nearest-even (finite inputs)
__device__ __forceinline__ unsigned short f2bf(float f) {
    unsigned u = __float_as_uint(f);
    unsigned r = ((u >> 16) & 1u) + 0x7fffu;
    return (unsigned short)((u + r) >> 16);
}
__device__ __forceinline__ float bflo(unsigned q) { return __uint_as_float(q << 16); }
__device__ __forceinline__ float bfhi(unsigned q) { return __uint_as_float(q & 0xffff0000u); }

// ---------------------------------------------------------------------------
// Skinny GEMM + attention-coefficient dots + per-block As-max (NO atomics):
//   H[n,:] = bf16(X[n,:] @ W) ;  As/Ad from full-precision acc;
//   bmax[blockIdx] = max As in block  (tiny reduce kernel folds to gmax).
// ---------------------------------------------------------------------------
template <int FIN, int FOUT, int CPR, int LCPR>
__global__ __launch_bounds__(256, 4) void gemm_rows(
    const float* __restrict__ X, const float* __restrict__ W,
    const float* __restrict__ a_src, const float* __restrict__ a_dst,
    unsigned short* __restrict__ H, float* __restrict__ As, float* __restrict__ Ad,
    float* __restrict__ bmax, int N)
{
    constexpr int ROWS = 256 / CPR;
    constexpr int XST = FIN + 4;              // padded row stride (floats)
    static_assert((1 << LCPR) == CPR && CPR * 4 == FOUT, "geometry");

    __shared__ float Ws[FIN * FOUT];
    __shared__ float Xs[ROWS * XST];
    __shared__ float wmax[4];

    const int tid = threadIdx.x;
    const int base = blockIdx.x * ROWS;

    for (int i = tid; i < FIN * FOUT / 4; i += 256)
        reinterpret_cast<float4*>(Ws)[i] = reinterpret_cast<const float4*>(W)[i];

    for (int i = tid; i < ROWS * FIN / 4; i += 256) {
        int row = i / (FIN / 4);
        int k4 = (i - row * (FIN / 4)) * 4;
        float4 v = make_float4(0.f, 0.f, 0.f, 0.f);
        if (base + row < N)
            v = *reinterpret_cast<const float4*>(&X[(size_t)(base + row) * FIN + k4]);
        *reinterpret_cast<float4*>(&Xs[row * XST + k4]) = v;
    }
    __syncthreads();

    const int colg = tid & (CPR - 1);
    const int row = tid >> LCPR;
    const int c0 = colg * 4;

    float4 acc = make_float4(0.f, 0.f, 0.f, 0.f);

#pragma unroll 2
    for (int k = 0; k < FIN; k += 4) {
        float4 xv = *reinterpret_cast<const float4*>(&Xs[row * XST + k]);
        float4 w0 = *reinterpret_cast<const float4*>(&Ws[(k + 0) * FOUT + c0]);
        float4 w1 = *reinterpret_cast<const float4*>(&Ws[(k + 1) * FOUT + c0]);
        float4 w2 = *reinterpret_cast<const float4*>(&Ws[(k + 2) * FOUT + c0]);
        float4 w3 = *reinterpret_cast<const float4*>(&Ws[(k + 3) * FOUT + c0]);
        acc.x = fmaf(xv.w, w3.x, fmaf(xv.z, w2.x, fmaf(xv.y, w1.x, fmaf(xv.x, w0.x, acc.x))));
        acc.y = fmaf(xv.w, w3.y, fmaf(xv.z, w2.y, fmaf(xv.y, w1.y, fmaf(xv.x, w0.y, acc.y))));
        acc.z = fmaf(xv.w, w3.z, fmaf(xv.z, w2.z, fmaf(xv.y, w1.z, fmaf(xv.x, w0.z, acc.z))));
        acc.w = fmaf(xv.w, w3.w, fmaf(xv.z, w2.w, fmaf(xv.y, w1.w, fmaf(xv.x, w0.w, acc.w))));
    }

    const int grow = base + row;
    if (grow < N) {
        ushort4 hv;
        hv.x = f2bf(acc.x); hv.y = f2bf(acc.y);
        hv.z = f2bf(acc.z); hv.w = f2bf(acc.w);
        *reinterpret_cast<ushort4*>(&H[(size_t)grow * FOUT + c0]) = hv;
    }

    float4 asv = *reinterpret_cast<const float4*>(&a_src[c0]);
    float4 adv = *reinterpret_cast<const float4*>(&a_dst[c0]);
    float ps = acc.x * asv.x + acc.y * asv.y + acc.z * asv.z + acc.w * asv.w;
    float pd = acc.x * adv.x + acc.y * adv.y + acc.z * adv.z + acc.w * adv.w;
#pragma unroll
    for (int ofs = 1; ofs < CPR; ofs <<= 1) {
        ps += __shfl_xor(ps, ofs);
        pd += __shfl_xor(pd, ofs);
    }
    if (colg == 0 && grow < N) { As[grow] = ps; Ad[grow] = pd; }

    // block max of As -> bmax[blockIdx] (no atomics)
    float pm = (grow < N) ? ps : -3.0e38f;
#pragma unroll
    for (int ofs = 1; ofs < 64; ofs <<= 1) pm = fmaxf(pm, __shfl_xor(pm, ofs));
    if ((tid & 63) == 0) wmax[tid >> 6] = pm;
    __syncthreads();
    if (tid == 0)
        bmax[blockIdx.x] = fmaxf(fmaxf(wmax[0], wmax[1]), fmaxf(wmax[2], wmax[3]));
}

// single block: gmax = max(bmax[0..nb))
__global__ __launch_bounds__(256) void reduce_max_kernel(
    const float* __restrict__ bmax, int nb, float* __restrict__ gmax)
{
    __shared__ float sd[256];
    const int t = threadIdx.x;
    float m = -3.0e38f;
    for (int i = t; i < nb; i += 256) m = fmaxf(m, bmax[i]);
    sd[t] = m; __syncthreads();
    for (int ofs = 128; ofs; ofs >>= 1) {
        if (t < ofs) sd[t] = fmaxf(sd[t], sd[t + ofs]);
        __syncthreads();
    }
    if (t == 0) *gmax = sd[0];
}

// one block, 64 threads: w2s[i] = sum_j W2[i][j]*a2s[j]; same for w2d.
__global__ __launch_bounds__(64) void w2prep(
    const float* __restrict__ W2, const float* __restrict__ a2s,
    const float* __restrict__ a2d, float* __restrict__ w2s, float* __restrict__ w2d)
{
    const int t = threadIdx.x;
    const int i = t & 31;
    const float* a = (t < 32) ? a2s : a2d;
    float s = 0.f;
    for (int j = 0; j < 64; ++j) s = fmaf(W2[i * 64 + j], a[j], s);
    if (t < 32) w2s[i] = s; else w2d[i] = s;
}

// per node (f32 h1a row, all 32 features): as2 = h1f . w2s ; ad2 = h1f . w2d.
__global__ __launch_bounds__(256) void alpha2_kernel(
    const float* __restrict__ h1f, const float* __restrict__ w2s,
    const float* __restrict__ w2d, float* __restrict__ As2, float* __restrict__ Ad2,
    float* __restrict__ bmaxa, int N)
{
    __shared__ float wmax[4];
    const int tid = threadIdx.x;
    const int n = blockIdx.x * 256 + tid;
    float ps = 0.f, pd = 0.f;
    if (n < N) {
        const float4* p = reinterpret_cast<const float4*>(h1f + (size_t)n * 32);
#pragma unroll
        for (int w = 0; w < 8; ++w) {
            float4 v = p[w];
            ps = fmaf(v.x, w2s[4 * w + 0], ps); ps = fmaf(v.y, w2s[4 * w + 1], ps);
            ps = fmaf(v.z, w2s[4 * w + 2], ps); ps = fmaf(v.w, w2s[4 * w + 3], ps);
            pd = fmaf(v.x, w2d[4 * w + 0], pd); pd = fmaf(v.y, w2d[4 * w + 1], pd);
            pd = fmaf(v.z, w2d[4 * w + 2], pd); pd = fmaf(v.w, w2d[4 * w + 3], pd);
        }
        As2[n] = ps; Ad2[n] = pd;
    }
    float pm = (n < N) ? ps : -3.0e38f;
#pragma unroll
    for (int ofs = 1; ofs < 64; ofs <<= 1) pm = fmaxf(pm, __shfl_xor(pm, ofs));
    if ((tid & 63) == 0) wmax[tid >> 6] = pm;
    __syncthreads();
    if (tid == 0)
        bmaxa[blockIdx.x] = fmaxf(fmaxf(wmax[0], wmax[1]), fmaxf(wmax[2], wmax[3]));
}

// ---------------------------------------------------------------------------
// CSR build (r13 form): 6 kernels, zero global atomics, no per-call memset.
// ---------------------------------------------------------------------------
__global__ __launch_bounds__(256) void chunk_hist(
    const int* __restrict__ dst, int* __restrict__ pcT,
    int E, int NB, int NCC, int NCH)
{
    __shared__ int hc[2048];
    const int t = threadIdx.x;
    for (int i = t; i < 2048; i += 256) hc[i] = 0;
    __syncthreads();
    const int base = blockIdx.x * PCHUNK;
    const int end = (base + PCHUNK < E) ? base + PCHUNK : E;
    for (int e = base + t; e < end; e += 256)
        atomicAdd(&hc[dst[e] >> BSH], 1);
    __syncthreads();
    if (t < NCC) {
        int f0 = t * RATIO;
        int s = 0;
#pragma unroll
        for (int j = 0; j < RATIO; ++j) {
            int fb = f0 + j;
            if (fb < NB) s += hc[fb];
        }
        pcT[(size_t)t * NCH + blockIdx.x] = s;
    }
}

__global__ __launch_bounds__(256) void coarse_total(
    const int* __restrict__ pcT, int* __restrict__ totals, int NCH)
{
    __shared__ int sd[256];
    const int t = threadIdx.x;
    int s = 0;
    for (int i = t; i < NCH; i += 256)
        s += pcT[(size_t)blockIdx.x * NCH + i];
    sd[t] = s; __syncthreads();
    for (int ofs = 128; ofs; ofs >>= 1) {
        if (t < ofs) sd[t] += sd[t + ofs];
        __syncthreads();
    }
    if (t == 0) totals[blockIdx.x] = sd[0];
}

__global__ __launch_bounds__(256) void boffc_scan(
    const int* __restrict__ totals, int* __restrict__ boffC, int NCC)
{
    __shared__ int sd[256];
    const int t = threadIdx.x;
    int v = (t < NCC) ? totals[t] : 0;
    sd[t] = v; __syncthreads();
    for (int ofs = 1; ofs < 256; ofs <<= 1) {
        int tmp = (t >= ofs) ? sd[t - ofs] : 0;
        __syncthreads();
        sd[t] += tmp;
        __syncthreads();
    }
    if (t < NCC) boffC[t] = sd[t] - v;
    if (t == 255) boffC[NCC] = sd[255];   // == E
}

__global__ __launch_bounds__(256) void coarse_scan(
    const int* __restrict__ pcT, const int* __restrict__ boffC,
    int* __restrict__ co, int NCH)
{
    __shared__ int sd[256];
    const int c = blockIdx.x;
    const int t = threadIdx.x;
    const int base = boffC[c];
    int carry = 0;
    for (int start = 0; start < NCH; start += 256) {
        int idx = start + t;
        int v = (idx < NCH) ? pcT[(size_t)c * NCH + idx] : 0;
        sd[t] = v; __syncthreads();
        for (int ofs = 1; ofs < 256; ofs <<= 1) {
            int tmp = (t >= ofs) ? sd[t - ofs] : 0;
            __syncthreads();
            sd[t] += tmp;
            __syncthreads();
        }
        int incl = sd[t];
        int total = sd[255];
        if (idx < NCH) co[(size_t)idx * 256 + c] = base + carry + incl - v;
        carry += total;
        __syncthreads();
    }
}

__global__ __launch_bounds__(256) void coarse_partition(
    const int* __restrict__ src, const int* __restrict__ dst,
    const int* __restrict__ co, int* __restrict__ csrA, int E, int NCC)
{
    __shared__ int lcur[256], gpos[256];
    const int t = threadIdx.x;
    lcur[t] = 0;
    if (t < NCC) gpos[t] = co[(size_t)blockIdx.x * 256 + t];
    __syncthreads();
    const int base = blockIdx.x * PCHUNK;
    int bb[32], pp[32];
#pragma unroll
    for (int i = 0; i < 32; ++i) {
        int e = base + i * 256 + t;
        bb[i] = -1;
        if (e < E) {
            int sv = src[e], dv = dst[e];
            bb[i] = dv >> CSH;
            pp[i] = (sv << CSH) | (dv & (CBN - 1));
        }
    }
#pragma unroll
    for (int i = 0; i < 32; ++i) {
        if (bb[i] >= 0) {
            int b = bb[i];
            csrA[gpos[b] + atomicAdd(&lcur[b], 1)] = pp[i];
        }
    }
}

__global__ __launch_bounds__(256) void node_sort(
    const int* __restrict__ csrA, const int* __restrict__ boffC,
    int* __restrict__ off, int* __restrict__ csr, int N, int NCC, int E)
{
    __shared__ int cnt[CBN];
    __shared__ int pref[CBN];
    __shared__ int sd[256];
    const int c = blockIdx.x;
    const int t = threadIdx.x;
    const int p0 = boffC[c];
    const int p1 = boffC[c + 1];
    const int n0 = c << CSH;

    for (int i = t; i < CBN; i += 256) cnt[i] = 0;
    __syncthreads();
    for (int i = p0 + t; i < p1; i += 256)
        atomicAdd(&cnt[csrA[i] & (CBN - 1)], 1);
    __syncthreads();
    int a0 = cnt[2 * t], a1 = cnt[2 * t + 1];
    int pairsum = a0 + a1;
    sd[t] = pairsum; __syncthreads();
    for (int ofs = 1; ofs < 256; ofs <<= 1) {
        int tmp = (t >= ofs) ? sd[t - ofs] : 0;
        __syncthreads();
        sd[t] += tmp;
        __syncthreads();
    }
    int run = sd[t] - pairsum;
    pref[2 * t] = run;
    pref[2 * t + 1] = run + a0;
    int n = n0 + 2 * t;
    if (n < N) off[n] = p0 + run;
    if (n + 1 < N) off[n + 1] = p0 + run + a0;
    if (c == NCC - 1 && t == 0) off[N] = E;
    __syncthreads();
    for (int i = t; i < CBN; i += 256) cnt[i] = 0;   // reuse as cursors
    __syncthreads();
    for (int i = p0 + t; i < p1; i += 256) {
        int v = csrA[i];
        int ln = v & (CBN - 1);
        int p = atomicAdd(&cnt[ln], 1);
        csr[p0 + pref[ln] + p] = v >> CSH;
    }
}

// ---------------------------------------------------------------------------
// Layer-1 aggregation: bf16 output (gather table for agg2) + f32 output
// (exact alpha2 input).
// ---------------------------------------------------------------------------
__global__ __launch_bounds__(256) void gat_agg1(
    const int* __restrict__ csr, const int* __restrict__ off,
    const float* __restrict__ As, const float* __restrict__ Ad,
    const unsigned short* __restrict__ Hb, const float* __restrict__ bias,
    const float* __restrict__ gmax, unsigned short* __restrict__ Out,
    float* __restrict__ OutF, int N)
{
    constexpr int LPR = 8;            // lanes per row (4 bf16 per lane)
    constexpr int EPI = 8;            // edges in flight
    constexpr unsigned RB = 64;       // row bytes

    __shared__ uint2 pr[4][64];
    const int wave = threadIdx.x >> 6;
    const int lane = threadIdx.x & 63;
    const int n = blockIdx.x * 4 + wave;
    if (n >= N) return;

    const int o0 = off[n];
    const int deg = off[n + 1] - o0;
    const float adn = Ad[n];
    const float eself = leaky(As[n] + adn);
    const float m = leaky(*gmax + adn);

    uint2* myp = pr[wave];
    const char* Hc = (const char*)Hb;
    const int subg = lane / LPR;
    const unsigned f8 = (unsigned)(lane & (LPR - 1)) * 8u;

    float4 acc = make_float4(0.f, 0.f, 0.f, 0.f);
    float denp = 0.f;

    for (int c = 0; c < deg; c += 64) {
        int i = c + lane;
        float w = 0.f; unsigned sb = 0;
        if (i < deg) {
            int s = csr[o0 + i];
            w = __expf(leaky(As[s] + adn) - m);
            sb = (unsigned)s * RB;
            denp += w;
        }
        myp[lane] = make_uint2(sb, __float_as_uint(w));
        int lim = (deg - c < 64) ? deg - c : 64;
        int j = subg;
        for (; j + 3 * EPI < lim; j += 4 * EPI) {
            uint2 p0 = myp[j], p1 = myp[j + EPI], p2 = myp[j + 2 * EPI], p3 = myp[j + 3 * EPI];
            uint2 q0 = *(const uint2*)(Hc + p0.x + f8);
            uint2 q1 = *(const uint2*)(Hc + p1.x + f8);
            uint2 q2 = *(const uint2*)(Hc + p2.x + f8);
            uint2 q3 = *(const uint2*)(Hc + p3.x + f8);
            float w0 = uf(p0.y), w1 = uf(p1.y), w2 = uf(p2.y), w3 = uf(p3.y);
            acc.x = fmaf(w0, bflo(q0.x), acc.x); acc.y = fmaf(w0, bfhi(q0.x), acc.y);
            acc.z = fmaf(w0, bflo(q0.y), acc.z); acc.w = fmaf(w0, bfhi(q0.y), acc.w);
            acc.x = fmaf(w1, bflo(q1.x), acc.x); acc.y = fmaf(w1, bfhi(q1.x), acc.y);
            acc.z = fmaf(w1, bflo(q1.y), acc.z); acc.w = fmaf(w1, bfhi(q1.y), acc.w);
            acc.x = fmaf(w2, bflo(q2.x), acc.x); acc.y = fmaf(w2, bfhi(q2.x), acc.y);
            acc.z = fmaf(w2, bflo(q2.y), acc.z); acc.w = fmaf(w2, bfhi(q2.y), acc.w);
            acc.x = fmaf(w3, bflo(q3.x), acc.x); acc.y = fmaf(w3, bfhi(q3.x), acc.y);
            acc.z = fmaf(w3, bflo(q3.y), acc.z); acc.w = fmaf(w3, bfhi(q3.y), acc.w);
        }
        for (; j < lim; j += EPI) {
            uint2 p = myp[j];
            uint2 q = *(const uint2*)(Hc + p.x + f8);
            float w0 = uf(p.y);
            acc.x = fmaf(w0, bflo(q.x), acc.x); acc.y = fmaf(w0, bfhi(q.x), acc.y);
            acc.z = fmaf(w0, bflo(q.y), acc.z); acc.w = fmaf(w0, bfhi(q.y), acc.w);
        }
    }

#pragma unroll
    for (int ofs = 32; ofs >= LPR; ofs >>= 1) {
        acc.x += __shfl_xor(acc.x, ofs);
        acc.y += __shfl_xor(acc.y, ofs);
        acc.z += __shfl_xor(acc.z, ofs);
        acc.w += __shfl_xor(acc.w, ofs);
    }
#pragma unroll
    for (int ofs = 1; ofs < 64; ofs <<= 1) denp += __shfl_xor(denp, ofs);

    float wsf = __expf(eself - m);
    uint2 qs = *(const uint2*)(Hc + (size_t)n * RB + f8);
    acc.x = fmaf(wsf, bflo(qs.x), acc.x); acc.y = fmaf(wsf, bfhi(qs.x), acc.y);
    acc.z = fmaf(wsf, bflo(qs.y), acc.z); acc.w = fmaf(wsf, bfhi(qs.y), acc.w);
    float den = denp + wsf;

    if (subg == 0) {
        int fi = (lane & (LPR - 1)) * 4;
        float4 bv = *reinterpret_cast<const float4*>(&bias[fi]);
        float vx = fmaxf(acc.x / den + bv.x, 0.f);
        float vy = fmaxf(acc.y / den + bv.y, 0.f);
        float vz = fmaxf(acc.z / den + bv.z, 0.f);
        float vw = fmaxf(acc.w / den + bv.w, 0.f);
        ushort4 hv;
        hv.x = f2bf(vx); hv.y = f2bf(vy); hv.z = f2bf(vz); hv.w = f2bf(vw);
        *reinterpret_cast<ushort4*>(&Out[(size_t)n * 32 + fi]) = hv;
        *reinterpret_cast<float4*>(&OutF[(size_t)n * 32 + fi]) =
            make_float4(vx, vy, vz, vw);
    }
}

// ---------------------------------------------------------------------------
// Layer-2 aggregation, fused @W2: gathers 64B bf16 h1a rows, aggregates
// agg32 = sum(alpha * h1a[s]) + self, then out = agg32@W2/den + b2.
// ---------------------------------------------------------------------------
__global__ __launch_bounds__(256) void gat_agg2(
    const int* __restrict__ csr, const int* __restrict__ off,
    const float* __restrict__ As, const float* __restrict__ Ad,
    const unsigned short* __restrict__ Hb, const float* __restrict__ W2,
    const float* __restrict__ b2, const float* __restrict__ gmax,
    float* __restrict__ Out, int N)
{
    constexpr int LPR = 8;
    constexpr int EPI = 8;
    constexpr unsigned RB = 64;

    __shared__ float Ws2[32 * 64];    // 8KB
    __shared__ uint2 pr[4][64];
    __shared__ float aggv[4][32];

    const int tid = threadIdx.x;
    for (int i = tid; i < 32 * 64 / 4; i += 256)
        reinterpret_cast<float4*>(Ws2)[i] = reinterpret_cast<const float4*>(W2)[i];
    __syncthreads();

    const int wave = tid >> 6;
    const int lane = tid & 63;
    const int n = blockIdx.x * 4 + wave;
    if (n >= N) return;

    const int o0 = off[n];
    const int deg = off[n + 1] - o0;
    const float adn = Ad[n];
    const float eself = leaky(As[n] + adn);
    const float m = leaky(*gmax + adn);

    uint2* myp = pr[wave];
    const char* Hc = (const char*)Hb;
    const int subg = lane / LPR;
    const unsigned f8 = (unsigned)(lane & (LPR - 1)) * 8u;

    float4 acc = make_float4(0.f, 0.f, 0.f, 0.f);
    float denp = 0.f;

    for (int c = 0; c < deg; c += 64) {
        int i = c + lane;
        float w = 0.f; unsigned sb = 0;
        if (i < deg) {
            int s = csr[o0 + i];
            w = __expf(leaky(As[s] + adn) - m);
            sb = (unsigned)s * RB;
            denp += w;
        }
        myp[lane] = make_uint2(sb, __float_as_uint(w));
        int lim = (deg - c < 64) ? deg - c : 64;
        int j = subg;
        for (; j + 3 * EPI < lim; j += 4 * EPI) {
            uint2 p0 = myp[j], p1 = myp[j + EPI], p2 = myp[j + 2 * EPI], p3 = myp[j + 3 * EPI];
            uint2 q0 = *(const uint2*)(Hc + p0.x + f8);
            uint2 q1 = *(const uint2*)(Hc + p1.x + f8);
            uint2 q2 = *(const uint2*)(Hc + p2.x + f8);
            uint2 q3 = *(const uint2*)(Hc + p3.x + f8);
            float w0 = uf(p0.y), w1 = uf(p1.y), w2 = uf(p2.y), w3 = uf(p3.y);
            acc.x = fmaf(w0, bflo(q0.x), acc.x); acc.y = fmaf(w0, bfhi(q0.x), acc.y);
            acc.z = fmaf(w0, bflo(q0.y), acc.z); acc.w = fmaf(w0, bfhi(q0.y), acc.w);
            acc.x = fmaf(w1, bflo(q1.x), acc.x); acc.y = fmaf(w1, bfhi(q1.x), acc.y);
            acc.z = fmaf(w1, bflo(q1.y), acc.z); acc.w = fmaf(w1, bfhi(q1.y), acc.w);
            acc.x = fmaf(w2, bflo(q2.x), acc.x); acc.y = fmaf(w2, bfhi(q2.x), acc.y);
            acc.z = fmaf(w2, bflo(q2.y), acc.z); acc.w = fmaf(w2, bfhi(q2.y), acc.w);
            acc.x = fmaf(w3, bflo(q3.x), acc.x); acc.y = fmaf(w3, bfhi(q3.x), acc.y);
            acc.z = fmaf(w3, bflo(q3.y), acc.z); acc.w = fmaf(w3, bfhi(q3.y), acc.w);
        }
        for (; j < lim; j += EPI) {
            uint2 p = myp[j];
            uint2 q = *(const uint2*)(Hc + p.x + f8);
            float w0 = uf(p.y);
            acc.x = fmaf(w0, bflo(q.x), acc.x); acc.y = fmaf(w0, bfhi(q.x), acc.y);
            acc.z = fmaf(w0, bflo(q.y), acc.z); acc.w = fmaf(w0, bfhi(q.y), acc.w);
        }
    }

#pragma unroll
    for (int ofs = 32; ofs >= LPR; ofs >>= 1) {
        acc.x += __shfl_xor(acc.x, ofs);
        acc.y += __shfl_xor(acc.y, ofs);
        acc.z += __shfl_xor(acc.z, ofs);
        acc.w += __shfl_xor(acc.w, ofs);
    }
#pragma unroll
    for (int ofs = 1; ofs < 64; ofs <<= 1) denp += __shfl_xor(denp, ofs);

    float wsf = __expf(eself - m);
    uint2 qs = *(const uint2*)(Hc + (size_t)n * RB + f8);
    acc.x = fmaf(wsf, bflo(qs.x), acc.x); acc.y = fmaf(wsf, bfhi(qs.x), acc.y);
    acc.z = fmaf(wsf, bflo(qs.y), acc.z); acc.w = fmaf(wsf, bfhi(qs.y), acc.w);
    float den = denp + wsf;

    if (subg == 0)
        *reinterpret_cast<float4*>(&aggv[wave][(lane & (LPR - 1)) * 4]) = acc;
    // same-wave LDS write->read is ordered; compiler inserts lgkmcnt wait

    float s = 0.f;
#pragma unroll
    for (int k = 0; k < 32; ++k)
        s = fmaf(aggv[wave][k], Ws2[k * 64 + lane], s);
    Out[(size_t)n * 64 + lane] = s / den + b2[lane];
}

// ---------------------------------------------------------------------------
extern "C" void kernel_launch(void* const* d_in, const int* in_sizes, int n_in,
                              void* d_out, int out_size, void* d_ws, size_t ws_size,
                              hipStream_t stream)
{
    const float* x   = (const float*)d_in[0];
    const int*   ei  = (const int*)d_in[1];   // [2, E] int32
    const float* W1  = (const float*)d_in[2];
    const float* a1s = (const float*)d_in[3];
    const float* a1d = (const float*)d_in[4];
    const float* b1  = (const float*)d_in[5];
    const float* W2  = (const float*)d_in[6];
    const float* a2s = (const float*)d_in[7];
    const float* a2d = (const float*)d_in[8];
    const float* b2  = (const float*)d_in[9];

    const int N = in_sizes[0] / 128;
    const int E = in_sizes[1] / 2;
    const int NB = (N + 63) >> BSH;                 // 64-node fine granularity
    const int NCC = (N + CBN - 1) >> CSH;           // coarse buckets (<=256)
    const int NCH = (E + PCHUNK - 1) / PCHUNK;
    const int* src = ei;
    const int* dst = ei + E;
    float* out = (float*)d_out;

    const int g1 = (N + 31) / 32;   // layer-1 gemm grid
    const int ga = (N + 255) / 256; // alpha2 grid

    // ---- workspace layout ----
    float* ws = (float*)d_ws;
    size_t o = 0;
    unsigned short* h1b = (unsigned short*)(ws + o); o += (size_t)N * 16;  // N*32 bf16
    unsigned short* h1a = (unsigned short*)(ws + o); o += (size_t)N * 16;  // N*32 bf16
    float* h1f = ws + o; o += (size_t)N * 32;                              // N*32 f32
    float* as1 = ws + o; o += N;
    float* ad1 = ws + o; o += N;
    float* as2 = ws + o; o += N;
    float* ad2 = ws + o; o += N;
    float* bmax = ws + o; o += (size_t)g1;
    float* bmaxa = ws + o; o += (size_t)ga;
    float* gmax1 = ws + o; o += 1;
    float* gmax2 = ws + o; o += 1;
    float* w2s = ws + o; o += 32;
    float* w2d = ws + o; o += 32;
    int* ip = (int*)(ws + o);
    size_t io = 0;
    int* pcT    = ip + io; io += (size_t)NCC * NCH;
    int* totals = ip + io; io += NCC;
    int* boffC  = ip + io; io += (NCC + 1);
    int* co     = ip + io; io += (size_t)NCH * 256;
    int* off    = ip + io; io += (N + 1);
    int* csrA   = ip + io; io += E;
    int* csr    = ip + io; io += E;

    // ---- CSR build (by dst), shared by both layers; zero global atomics ----
    chunk_hist<<<NCH, 256, 0, stream>>>(dst, pcT, E, NB, NCC, NCH);
    coarse_total<<<NCC, 256, 0, stream>>>(pcT, totals, NCH);
    boffc_scan<<<1, 256, 0, stream>>>(totals, boffC, NCC);
    coarse_scan<<<NCC, 256, 0, stream>>>(pcT, boffC, co, NCH);
    coarse_partition<<<NCH, 256, 0, stream>>>(src, dst, co, csrA, E, NCC);
    node_sort<<<NCC, 256, 0, stream>>>(csrA, boffC, off, csr, N, NCC, E);

    const int gn = (N + 3) / 4;

    // ---- layer 1 (FIN=128 -> 32) ----
    gemm_rows<128, 32, 8, 3><<<g1, 256, 0, stream>>>(
        x, W1, a1s, a1d, h1b, as1, ad1, bmax, N);
    reduce_max_kernel<<<1, 256, 0, stream>>>(bmax, g1, gmax1);
    gat_agg1<<<gn, 256, 0, stream>>>(
        csr, off, as1, ad1, h1b, b1, gmax1, h1a, h1f, N);

    // ---- layer 2 (32 -> 64), gemm folded into aggregation ----
    w2prep<<<1, 64, 0, stream>>>(W2, a2s, a2d, w2s, w2d);
    alpha2_kernel<<<ga, 256, 0, stream>>>(h1f, w2s, w2d, as2, ad2, bmaxa, N);
    reduce_max_kernel<<<1, 256, 0, stream>>>(bmaxa, ga, gmax2);
    gat_agg2<<<gn, 256, 0, stream>>>(
        csr, off, as2, ad2, h1a, W2, b2, gmax2, out, N);
}